// Round 14
// baseline (562.120 us; speedup 1.0000x reference)
//
#include <hip/hip_runtime.h>
#include <hip/hip_bf16.h>
#include <cstdint>
#include <cstddef>

#define DEV static __device__ __forceinline__

constexpr int GRAPHS = 128;
constexpr int NPG    = 1000;   // nodes per graph
constexpr int EPG    = 4000;   // edges per graph
constexpr int TOTN   = GRAPHS * NPG;  // 128000
constexpr int TOTE   = GRAPHS * EPG;  // 512000
constexpr int HD     = 64;
constexpr int OBSD   = 1500;
constexpr int AD     = 15;

typedef __attribute__((ext_vector_type(8))) short bf16x8;
typedef __attribute__((ext_vector_type(4))) float f32x4;

// ---------- helpers ----------
DEV unsigned short f2b(float f){   // round-to-nearest-even bf16
  unsigned u = __float_as_uint(f);
  return (unsigned short)((u + 0x7fffu + ((u >> 16) & 1u)) >> 16);
}
DEV float b2f(unsigned short s){ return __uint_as_float((unsigned)s << 16); }

DEV void fma4(float4& a, float s, const float4 w){
  a.x = fmaf(s, w.x, a.x); a.y = fmaf(s, w.y, a.y);
  a.z = fmaf(s, w.z, a.z); a.w = fmaf(s, w.w, a.w);
}

DEV ushort4 pack4(float4 v){
  ushort4 r; r.x=f2b(v.x); r.y=f2b(v.y); r.z=f2b(v.z); r.w=f2b(v.w); return r;
}

// ---------- weight prep: pack all layer weights to bf16 W^T ----------
// per layer (stride 32768 bf16): qkvT[192][64] | woT[64][64] | w1T[128][64] | w2T[64][128]
__global__ __launch_bounds__(256) void k_wprep(const float* __restrict__ Wq,
    const float* __restrict__ Wk, const float* __restrict__ Wv,
    const float* __restrict__ Wo, const float* __restrict__ W1,
    const float* __restrict__ W2, unsigned short* __restrict__ wpack){
  int e = blockIdx.x*256 + threadIdx.x;
  int l = e >> 15;
  int r = e & 32767;
  float val;
  if (r < 12288){
    int c = r >> 6, k = r & 63;
    val = (c < 64)  ? Wq[l*4096 + k*64 + c]
        : (c < 128) ? Wk[l*4096 + k*64 + (c-64)]
                    : Wv[l*4096 + k*64 + (c-128)];
  } else if (r < 16384){
    int i = r - 12288; int c = i >> 6, k = i & 63;
    val = Wo[l*4096 + k*64 + c];
  } else if (r < 24576){
    int i = r - 16384; int c = i >> 6, k = i & 63;
    val = W1[l*8192 + k*128 + c];
  } else {
    int i = r - 24576; int c = i >> 7, k = i & 127;
    val = W2[l*8192 + k*64 + c];
  }
  wpack[e] = f2b(val);
}

// ---------- CSR build (once per call; reused by all 4 layers) ----------
__global__ __launch_bounds__(256) void k_zero(int* __restrict__ cnt){
  cnt[blockIdx.x*256 + threadIdx.x] = 0;
}

__global__ __launch_bounds__(256) void k_hist(const int* __restrict__ edst,
                                              int* __restrict__ cnt){
  int e = blockIdx.x*256 + threadIdx.x;
  atomicAdd(&cnt[edst[e]], 1);
}

__global__ __launch_bounds__(1024) void k_scan(const int* __restrict__ cnt,
    int* __restrict__ rstart, int* __restrict__ cursor){
  __shared__ int s[1024];
  const int g = blockIdx.x, tid = threadIdx.x;
  int v = (tid < NPG) ? cnt[g*NPG + tid] : 0;
  s[tid] = v;
  __syncthreads();
  #pragma unroll
  for (int off=1; off<1024; off<<=1){
    int t = (tid >= off) ? s[tid-off] : 0;
    __syncthreads();
    s[tid] += t;
    __syncthreads();
  }
  if (tid < NPG){
    int r = g*EPG + (s[tid] - v);
    rstart[g*NPG+tid] = r;
    cursor[g*NPG+tid] = r;
  }
}

__global__ __launch_bounds__(256) void k_scatter(const int* __restrict__ esrc,
    const int* __restrict__ edst, int* __restrict__ cursor,
    int* __restrict__ esorted){
  int e = blockIdx.x*256 + threadIdx.x;
  int pos = atomicAdd(&cursor[edst[e]], 1);
  esorted[pos] = esrc[e];
}

// ---------- K1: x(bf16) = node_feats @ W_in  [128000,32]x[32,64] ----------
__global__ __launch_bounds__(256) void k_in(const float* __restrict__ nf,
                                            const float* __restrict__ Win,
                                            unsigned short* __restrict__ xb){
  __shared__ float  s_nf[256*36];
  __shared__ float4 s_w[512];
  const int tid = threadIdx.x;
  const int node0 = blockIdx.x * 256;
  const float4* W4 = (const float4*)Win;
  s_w[tid] = W4[tid]; s_w[tid+256] = W4[tid+256];
  const float4* nf4 = (const float4*)nf;
  float4* snf4 = (float4*)s_nf;
  #pragma unroll
  for (int r=0;r<8;r++){
    int i = tid + 256*r; int n = i>>3, k4 = i&7;
    snf4[n*9 + k4] = nf4[(size_t)(node0+n)*8 + k4];
  }
  __syncthreads();
  const int ng = tid>>2, cg = tid&3;
  float4 acc[4][4];
  #pragma unroll
  for (int i=0;i<4;i++){ acc[i][0]=make_float4(0,0,0,0); acc[i][1]=make_float4(0,0,0,0);
                         acc[i][2]=make_float4(0,0,0,0); acc[i][3]=make_float4(0,0,0,0); }
  #pragma unroll 4
  for (int k=0;k<32;k++){
    float nv[4];
    #pragma unroll
    for (int i=0;i<4;i++) nv[i] = s_nf[(ng + 64*i)*36 + k];
    float4 w[4];
    #pragma unroll
    for (int j=0;j<4;j++) w[j] = s_w[k*16 + cg*4 + j];
    #pragma unroll
    for (int i=0;i<4;i++){
      #pragma unroll
      for (int j=0;j<4;j++) fma4(acc[i][j], nv[i], w[j]);
    }
  }
  ushort4* xb4 = (ushort4*)xb;
  #pragma unroll
  for (int i=0;i<4;i++){
    size_t nidx = (size_t)(node0 + ng + 64*i) * 16;
    #pragma unroll
    for (int j=0;j<4;j++) xb4[nidx + cg*4 + j] = pack4(acc[i][j]);
  }
}

// ---------- K2 (MFMA): qkv(bf16) = x @ [Wq|Wk|Wv], 256 nodes/block ----------
__global__ __launch_bounds__(256) void k_qkv_m(const unsigned short* __restrict__ xb,
    const unsigned short* __restrict__ wqkvT,   // [192][64] bf16
    unsigned short* __restrict__ qkv){
  __shared__ short s_w[192*72];        // 27.6KB
  __shared__ short s_st[4][16*104];    // 13.3KB; pitch 104 (208B, 16B-aligned)
  const int tid = threadIdx.x;
  const int node0 = blockIdx.x * 256;
  {
    const unsigned* src = (const unsigned*)wqkvT;
    unsigned* dst = (unsigned*)s_w;
    #pragma unroll
    for (int r=0;r<24;r++){
      int j = tid + 256*r;
      int c = j >> 5, kk = j & 31;
      dst[c*36 + kk] = src[j];
    }
  }
  __syncthreads();
  const int lane = tid & 63, wave = tid >> 6;
  const int m = lane & 15, quad = lane >> 4;
  const int rowbase = node0 + wave*64;
  bf16x8 af[4][2];
  #pragma unroll
  for (int rt=0;rt<4;rt++){
    const unsigned short* xp = xb + (size_t)(rowbase + rt*16 + m)*64 + quad*8;
    af[rt][0] = *(const bf16x8*)xp;
    af[rt][1] = *(const bf16x8*)(xp + 32);
  }
  short* st = s_st[wave];
  #pragma unroll
  for (int rt=0;rt<4;rt++){
    #pragma unroll
    for (int half=0; half<2; half++){
      #pragma unroll
      for (int c6=0;c6<6;c6++){
        int ct = half*6 + c6;
        bf16x8 b0 = *(const bf16x8*)&s_w[(ct*16+m)*72 + quad*8];
        bf16x8 b1 = *(const bf16x8*)&s_w[(ct*16+m)*72 + 32 + quad*8];
        f32x4 acc = {0.f,0.f,0.f,0.f};
        acc = __builtin_amdgcn_mfma_f32_16x16x32_bf16(af[rt][0], b0, acc, 0,0,0);
        acc = __builtin_amdgcn_mfma_f32_16x16x32_bf16(af[rt][1], b1, acc, 0,0,0);
        #pragma unroll
        for (int i=0;i<4;i++)
          st[(quad*4+i)*104 + c6*16 + m] = (short)f2b(acc[i]);
      }
      // coalesced writeout of this 16x96 half-tile
      #pragma unroll
      for (int j=0;j<3;j++){
        int flat = (j*64 + lane)*8;
        int r = flat / 96, c = flat % 96;
        bf16x8 v = *(const bf16x8*)&st[r*104 + c];
        *(bf16x8*)(qkv + (size_t)(rowbase + rt*16 + r)*192 + half*96 + c) = v;
      }
    }
  }
}

// ---------- K4: edge attention, neighbor-parallel: 1 wave/node ----------
// lane = (quad, dg): quad = neighbor slot (4 concurrent), dg = dim-group.
// Serial neighbor chain collapses from deg to ceil(deg/4) iterations.
__global__ __launch_bounds__(256) void k_edge3(const unsigned short* __restrict__ qkv,
    const int* __restrict__ rstart, const int* __restrict__ cnt,
    const int* __restrict__ esorted, unsigned short* __restrict__ attn_in){
  const int tid  = threadIdx.x;
  const int wave = tid >> 6, lane = tid & 63;
  const int quad = lane >> 4, dg = lane & 15;
  // XCD swizzle: 32000 units of 4 nodes; per-XCD slice covers 16 contiguous graphs
  const int unit = (blockIdx.x & 7)*4000 + (blockIdx.x >> 3);
  const int node = unit*4 + wave;
  ushort4 qu = *(const ushort4*)(qkv + (size_t)node*192 + dg*4);
  float q0 = b2f(qu.x), q1 = b2f(qu.y), q2 = b2f(qu.z), q3 = b2f(qu.w);
  const int rs = rstart[node];
  const int n  = cnt[node];
  float a0=0.f, a1=0.f, a2=0.f, a3=0.f, den=0.f;
  for (int j=0; j*4 < n; j++){
    int i = j*4 + quad;
    bool valid = (i < n);
    int src = valid ? esorted[rs + i] : node;
    ushort4 ku = *(const ushort4*)(qkv + (size_t)src*192 + 64 + dg*4);
    ushort4 vu = *(const ushort4*)(qkv + (size_t)src*192 + 128 + dg*4);
    float p = q0*b2f(ku.x) + q1*b2f(ku.y) + q2*b2f(ku.z) + q3*b2f(ku.w);
    p += __shfl_xor(p, 1);
    p += __shfl_xor(p, 2);          // head-sum within quad (validity quad-uniform)
    float w = valid ? __expf(p * 0.25f) : 0.f;   // softmax shift-invariant
    den += w;
    a0 = fmaf(w, b2f(vu.x), a0);
    a1 = fmaf(w, b2f(vu.y), a1);
    a2 = fmaf(w, b2f(vu.z), a2);
    a3 = fmaf(w, b2f(vu.w), a3);
  }
  // cross-quad (neighbor-slot) reduction
  den += __shfl_xor(den, 16); den += __shfl_xor(den, 32);
  a0  += __shfl_xor(a0, 16);  a0  += __shfl_xor(a0, 32);
  a1  += __shfl_xor(a1, 16);  a1  += __shfl_xor(a1, 32);
  a2  += __shfl_xor(a2, 16);  a2  += __shfl_xor(a2, 32);
  a3  += __shfl_xor(a3, 16);  a3  += __shfl_xor(a3, 32);
  if (quad == 0){
    float inv = 1.0f/(den + 1e-9f);
    ushort4 o;
    o.x = f2b(a0*inv); o.y = f2b(a1*inv); o.z = f2b(a2*inv); o.w = f2b(a3*inv);
    ((ushort4*)attn_in)[(size_t)node*16 + dg] = o;
  }
}

// ---------- K5 (MFMA): fused attn-proj + LN1 + ffn + LN2, 256 nodes/block ----
// LDS = 18432 + 17408 + 17408 = 53.2 KB -> 3 blocks/CU.
__global__ __launch_bounds__(256) void k_attn_ffn(
    const unsigned short* __restrict__ attn_in,
    unsigned short* __restrict__ xb,
    const unsigned short* __restrict__ woT,    // [64][64]
    const unsigned short* __restrict__ w1T, const float* __restrict__ b1_l,
    const unsigned short* __restrict__ w2T, const float* __restrict__ b2_l,
    const float* __restrict__ l1g, const float* __restrict__ l1b,
    const float* __restrict__ l2g, const float* __restrict__ l2b){
  __shared__ short s_w1[128*72];      // 18.4KB
  __shared__ short s_w2[64*136];      // 17.4KB
  __shared__ short s_st[4][16*136];   // 17.4KB per-wave stage (x1 then h then out)
  const int tid = threadIdx.x;
  const int node0 = blockIdx.x*256;
  {
    const unsigned* src = (const unsigned*)w1T;
    unsigned* dst = (unsigned*)s_w1;
    #pragma unroll
    for (int r=0;r<16;r++){
      int j = tid + 256*r;
      int c = j >> 5, kk = j & 31;
      dst[c*36 + kk] = src[j];
    }
  }
  {
    const unsigned* src = (const unsigned*)w2T;
    unsigned* dst = (unsigned*)s_w2;
    #pragma unroll
    for (int r=0;r<16;r++){
      int j = tid + 256*r;
      int c = j >> 6, kk = j & 63;
      dst[c*68 + kk] = src[j];
    }
  }
  const int lane = tid&63, wave = tid>>6;
  const int m = lane&15, quad = lane>>4;
  const int rowbase = node0 + wave*64;
  bf16x8 wo[4][2];
  #pragma unroll
  for (int ct=0;ct<4;ct++){
    wo[ct][0] = *(const bf16x8*)&woT[(ct*16+m)*64 + quad*8];
    wo[ct][1] = *(const bf16x8*)&woT[(ct*16+m)*64 + 32 + quad*8];
  }
  float g1[4], bb1[4], g2[4], bb2[4], b2v[4];
  #pragma unroll
  for (int ct=0;ct<4;ct++){
    g1[ct]=l1g[ct*16+m]; bb1[ct]=l1b[ct*16+m];
    g2[ct]=l2g[ct*16+m]; bb2[ct]=l2b[ct*16+m];
    b2v[ct]=b2_l[ct*16+m];
  }
  float b1v[8];
  #pragma unroll
  for (int ct=0;ct<8;ct++) b1v[ct]=b1_l[ct*16+m];
  bf16x8 af[4][2];
  #pragma unroll
  for (int rt=0;rt<4;rt++){
    const unsigned short* ap = attn_in + (size_t)(rowbase + rt*16 + m)*64 + quad*8;
    af[rt][0] = *(const bf16x8*)ap;
    af[rt][1] = *(const bf16x8*)(ap + 32);
  }
  __syncthreads();
  short* st = s_st[wave];
  #pragma unroll
  for (int rt=0;rt<4;rt++){
    // ---- attn projection ----
    f32x4 acc[4];
    #pragma unroll
    for (int ct=0;ct<4;ct++){
      f32x4 z = {0.f,0.f,0.f,0.f};
      z = __builtin_amdgcn_mfma_f32_16x16x32_bf16(af[rt][0], wo[ct][0], z, 0,0,0);
      z = __builtin_amdgcn_mfma_f32_16x16x32_bf16(af[rt][1], wo[ct][1], z, 0,0,0);
      acc[ct] = z;
    }
    // ---- residual + LN1 -> x1 (registers, C-layout) + stage cols 0..63 ----
    float x1v[4][4];
    #pragma unroll
    for (int i=0;i<4;i++){
      size_t row = (size_t)(rowbase + rt*16 + quad*4 + i)*64;
      float v0 = acc[0][i] + b2f(xb[row + m]);
      float v1 = acc[1][i] + b2f(xb[row + 16 + m]);
      float v2 = acc[2][i] + b2f(xb[row + 32 + m]);
      float v3 = acc[3][i] + b2f(xb[row + 48 + m]);
      float sm = v0+v1+v2+v3;
      float sq = v0*v0+v1*v1+v2*v2+v3*v3;
      #pragma unroll
      for (int mk=1; mk<16; mk<<=1){ sm += __shfl_xor(sm, mk); sq += __shfl_xor(sq, mk); }
      float mean = sm*0.015625f;
      float var  = sq*0.015625f - mean*mean;
      float rs   = rsqrtf(var + 1e-5f);
      x1v[i][0] = (v0-mean)*rs*g1[0]+bb1[0];
      x1v[i][1] = (v1-mean)*rs*g1[1]+bb1[1];
      x1v[i][2] = (v2-mean)*rs*g1[2]+bb1[2];
      x1v[i][3] = (v3-mean)*rs*g1[3]+bb1[3];
      int rl = quad*4 + i;
      st[rl*136 + m]      = (short)f2b(x1v[i][0]);
      st[rl*136 + 16 + m] = (short)f2b(x1v[i][1]);
      st[rl*136 + 32 + m] = (short)f2b(x1v[i][2]);
      st[rl*136 + 48 + m] = (short)f2b(x1v[i][3]);
    }
    // ---- ffn1 A-frags from stage ----
    bf16x8 x10 = *(const bf16x8*)&st[m*136 + quad*8];
    bf16x8 x11 = *(const bf16x8*)&st[m*136 + 32 + quad*8];
    // ---- ffn1: h = relu(x1@W1+b1) into stage ----
    #pragma unroll
    for (int ct=0;ct<8;ct++){
      bf16x8 b0 = *(const bf16x8*)&s_w1[(ct*16+m)*72 + quad*8];
      bf16x8 b1 = *(const bf16x8*)&s_w1[(ct*16+m)*72 + 32 + quad*8];
      f32x4 z = {0.f,0.f,0.f,0.f};
      z = __builtin_amdgcn_mfma_f32_16x16x32_bf16(x10, b0, z, 0,0,0);
      z = __builtin_amdgcn_mfma_f32_16x16x32_bf16(x11, b1, z, 0,0,0);
      #pragma unroll
      for (int i=0;i<4;i++)
        st[(quad*4+i)*136 + ct*16 + m] = (short)f2b(fmaxf(z[i]+b1v[ct], 0.f));
    }
    // ---- ffn2 ----
    bf16x8 h0 = *(const bf16x8*)&st[m*136 + quad*8];
    bf16x8 h1 = *(const bf16x8*)&st[m*136 + 32 + quad*8];
    bf16x8 h2 = *(const bf16x8*)&st[m*136 + 64 + quad*8];
    bf16x8 h3 = *(const bf16x8*)&st[m*136 + 96 + quad*8];
    f32x4 acc2[4];
    #pragma unroll
    for (int ct=0;ct<4;ct++){
      f32x4 z = {0.f,0.f,0.f,0.f};
      z = __builtin_amdgcn_mfma_f32_16x16x32_bf16(h0, *(const bf16x8*)&s_w2[(ct*16+m)*136 + quad*8],      z, 0,0,0);
      z = __builtin_amdgcn_mfma_f32_16x16x32_bf16(h1, *(const bf16x8*)&s_w2[(ct*16+m)*136 + 32 + quad*8], z, 0,0,0);
      z = __builtin_amdgcn_mfma_f32_16x16x32_bf16(h2, *(const bf16x8*)&s_w2[(ct*16+m)*136 + 64 + quad*8], z, 0,0,0);
      z = __builtin_amdgcn_mfma_f32_16x16x32_bf16(h3, *(const bf16x8*)&s_w2[(ct*16+m)*136 + 96 + quad*8], z, 0,0,0);
      acc2[ct] = z;
    }
    // ---- residual (x1 registers) + b2 + LN2 -> stage cols 0..63 ----
    #pragma unroll
    for (int i=0;i<4;i++){
      float v0 = acc2[0][i] + b2v[0] + x1v[i][0];
      float v1 = acc2[1][i] + b2v[1] + x1v[i][1];
      float v2 = acc2[2][i] + b2v[2] + x1v[i][2];
      float v3 = acc2[3][i] + b2v[3] + x1v[i][3];
      float sm = v0+v1+v2+v3;
      float sq = v0*v0+v1*v1+v2*v2+v3*v3;
      #pragma unroll
      for (int mk=1; mk<16; mk<<=1){ sm += __shfl_xor(sm, mk); sq += __shfl_xor(sq, mk); }
      float mean = sm*0.015625f;
      float var  = sq*0.015625f - mean*mean;
      float rs   = rsqrtf(var + 1e-5f);
      int rl = quad*4 + i;
      st[rl*136 + m]      = (short)f2b((v0-mean)*rs*g2[0]+bb2[0]);
      st[rl*136 + 16 + m] = (short)f2b((v1-mean)*rs*g2[1]+bb2[1]);
      st[rl*136 + 32 + m] = (short)f2b((v2-mean)*rs*g2[2]+bb2[2]);
      st[rl*136 + 48 + m] = (short)f2b((v3-mean)*rs*g2[3]+bb2[3]);
    }
    // ---- coalesced store of new x ----
    #pragma unroll
    for (int j=0;j<2;j++){
      int flat = (j*64 + lane)*8;
      int r = flat >> 6, c = flat & 63;
      bf16x8 v = *(const bf16x8*)&st[r*136 + c];
      *(bf16x8*)(xb + (size_t)(rowbase + rt*16 + r)*64 + c) = v;
    }
  }
}

// ---------- heads: FC1 with inline feat assembly (gat_out + obs) ----------
__global__ __launch_bounds__(512) void k_fc1(const unsigned short* __restrict__ xb,
    const float* __restrict__ obs, const int* __restrict__ agents,
    const float* __restrict__ Wr, const float* __restrict__ br,
    const float* __restrict__ Wp1, float* __restrict__ part1){
  constexpr int ROWS=2, COLS=256, CH=384, K=1515, N=512;
  const int chunk = 379;
  __shared__ float s_a[ROWS*CH];
  const int tid = threadIdx.x;
  const int ct = blockIdx.x, rg = blockIdx.y, ks = blockIdx.z;
  const int k0 = ks * chunk;
  const int len = min(K - k0, chunk);
  const int row0 = rg * ROWS;
  #pragma unroll
  for (int rr=0; rr<ROWS; rr++)
    for (int i=tid; i<len; i+=512){
      int k = k0 + i;
      if (k >= AD) s_a[rr*CH + i] = obs[(size_t)(row0+rr)*OBSD + (k-AD)];
    }
  if (ks==0 && tid < ROWS*AD){
    int rr = tid/AD, c = tid%AD;
    int b = row0 + rr;
    const unsigned short* xa = xb + (size_t)agents[b]*HD;
    float a = br[c];
    #pragma unroll 8
    for (int k=0;k<HD;k++) a = fmaf(b2f(xa[k]), Wr[k*AD + c], a);
    s_a[rr*CH + c] = a;
  }
  __syncthreads();
  const int r = tid / COLS, c = tid % COLS;
  const float* wp = Wp1 + (size_t)k0*N + ct*COLS + c;
  const float* ap = s_a + r*CH;
  float acc = 0.f;
  #pragma unroll 8
  for (int k=0;k<len;k++) acc = fmaf(ap[k], wp[(size_t)k*N], acc);
  part1[((size_t)ks*128 + row0 + r)*N + ct*COLS + c] = acc;
}

// ---------- heads: FC2 with reduce+tanh on A-load ----------
__global__ __launch_bounds__(512) void k_fc2(const float* __restrict__ part1,
    const float* __restrict__ bp1, const float* __restrict__ Wp2,
    float* __restrict__ part2){
  constexpr int ROWS=2, COLS=256, CH=256, N=512;
  __shared__ float s_a[ROWS*CH];
  const int tid = threadIdx.x;
  const int ct = blockIdx.x, rg = blockIdx.y, ks = blockIdx.z;
  const int k0 = ks * CH;
  const int row0 = rg * ROWS;
  #pragma unroll
  for (int rr=0; rr<ROWS; rr++)
    for (int i=tid; i<CH; i+=512){
      int k = k0 + i;
      float s = bp1[k];
      #pragma unroll
      for (int j=0;j<4;j++) s += part1[((size_t)j*128 + row0+rr)*512 + k];
      s_a[rr*CH + i] = tanhf(s);
    }
  __syncthreads();
  const int r = tid / COLS, c = tid % COLS;
  const float* wp = Wp2 + (size_t)k0*N + ct*COLS + c;
  const float* ap = s_a + r*CH;
  float acc = 0.f;
  #pragma unroll 8
  for (int k=0;k<CH;k++) acc = fmaf(ap[k], wp[(size_t)k*N], acc);
  part2[((size_t)ks*128 + row0 + r)*N + ct*COLS + c] = acc;
}

// ---------- heads: logits with reduce+tanh on load ----------
__global__ __launch_bounds__(256) void k_logits(const float* __restrict__ part2,
    const float* __restrict__ bp2, const float* __restrict__ Wlog,
    const float* __restrict__ blog, float* __restrict__ out){
  __shared__ float s_f[512];
  __shared__ float s_p[16*AD];
  const int b = blockIdx.x, tid = threadIdx.x;
  for (int i=tid;i<512;i+=256){
    float s = bp2[i] + part2[(size_t)b*512 + i] + part2[(size_t)(128+b)*512 + i];
    s_f[i] = tanhf(s);
  }
  __syncthreads();
  if (tid < 240){
    int c = tid % AD, kc = tid / AD;
    float a = 0.f;
    #pragma unroll 8
    for (int j=0;j<32;j++){ int k = kc*32 + j; a = fmaf(s_f[k], Wlog[k*AD + c], a); }
    s_p[tid] = a;
  }
  __syncthreads();
  if (tid < AD){
    float a = blog[tid];
    #pragma unroll
    for (int kc=0;kc<16;kc++) a += s_p[kc*AD + tid];
    out[(size_t)b*AD + tid] = a;
  }
}

// ---------- heads: value split-K GEMM ----------
template<int ROWS, int COLS, int CH, int KS, int N>
__global__ __launch_bounds__(ROWS*COLS) void k_gemm_part(
    const float* __restrict__ A, int lda, int K,
    const float* __restrict__ W, float* __restrict__ part){
  constexpr int BT = ROWS*COLS;
  __shared__ float s_a[ROWS*CH];
  const int tid = threadIdx.x;
  const int ct = blockIdx.x, rg = blockIdx.y, ks = blockIdx.z;
  const int chunk = (K + KS - 1) / KS;
  const int k0 = ks * chunk;
  const int len = min(K - k0, chunk);
  const int row0 = rg * ROWS;
  #pragma unroll
  for (int rr=0; rr<ROWS; rr++)
    for (int i=tid; i<len; i+=BT)
      s_a[rr*CH + i] = A[(size_t)(row0+rr)*lda + k0 + i];
  __syncthreads();
  const int r = tid / COLS, c = tid % COLS;
  const float* wp = W + (size_t)k0*N + ct*COLS + c;
  const float* ap = s_a + r*CH;
  float acc = 0.f;
  #pragma unroll 8
  for (int k=0;k<len;k++) acc = fmaf(ap[k], wp[(size_t)k*N], acc);
  part[((size_t)ks*128 + row0 + r)*N + ct*COLS + c] = acc;
}

// ---------- heads: value finish with reduce+tanh on load ----------
__global__ __launch_bounds__(128) void k_vfin(const float* __restrict__ partv,
    const float* __restrict__ bv1, const float* __restrict__ Wv2,
    const float* __restrict__ bv2, const float* __restrict__ Wvo,
    const float* __restrict__ bvo, float* __restrict__ out){
  __shared__ float s_v[128];
  __shared__ float s_r[128];
  const int b = blockIdx.x, tid = threadIdx.x;
  {
    float s = bv1[tid];
    #pragma unroll
    for (int j=0;j<8;j++) s += partv[((size_t)j*128 + b)*128 + tid];
    s_v[tid] = tanhf(s);
  }
  __syncthreads();
  float a = bv2[tid];
  #pragma unroll 8
  for (int k=0;k<128;k++) a = fmaf(s_v[k], Wv2[k*128 + tid], a);
  s_r[tid] = tanhf(a) * Wvo[tid];
  __syncthreads();
  if (tid < 64){
    float v = s_r[tid] + s_r[tid+64];
    #pragma unroll
    for (int m=32;m>=1;m>>=1) v += __shfl_xor(v, m);
    if (tid==0) out[GRAPHS*AD + b] = v + bvo[0];
  }
}

// ---------- launch ----------
extern "C" void kernel_launch(void* const* d_in, const int* in_sizes, int n_in,
                              void* d_out, int out_size, void* d_ws, size_t ws_size,
                              hipStream_t stream) {
  (void)in_sizes; (void)n_in; (void)out_size; (void)ws_size;
  const float* nf     = (const float*)d_in[0];
  const float* obs    = (const float*)d_in[1];
  const int*   esrc   = (const int*)d_in[2];
  const int*   edst   = (const int*)d_in[3];
  const int*   agents = (const int*)d_in[4];
  const float* Win    = (const float*)d_in[5];
  const float* Wq     = (const float*)d_in[6];
  const float* Wk     = (const float*)d_in[7];
  const float* Wv     = (const float*)d_in[8];
  const float* Wo     = (const float*)d_in[9];
  const float* ln1g   = (const float*)d_in[10];
  const float* ln1b   = (const float*)d_in[11];
  const float* W1     = (const float*)d_in[12];
  const float* b1     = (const float*)d_in[13];
  const float* W2     = (const float*)d_in[14];
  const float* b2     = (const float*)d_in[15];
  const float* ln2g   = (const float*)d_in[16];
  const float* ln2b   = (const float*)d_in[17];
  const float* Wr     = (const float*)d_in[18];
  const float* br     = (const float*)d_in[19];
  const float* Wp1    = (const float*)d_in[20];
  const float* bp1    = (const float*)d_in[21];
  const float* Wp2    = (const float*)d_in[22];
  const float* bp2    = (const float*)d_in[23];
  const float* Wlog   = (const float*)d_in[24];
  const float* blog   = (const float*)d_in[25];
  const float* Wv1    = (const float*)d_in[26];
  const float* bv1    = (const float*)d_in[27];
  const float* Wv2    = (const float*)d_in[28];
  const float* bv2    = (const float*)d_in[29];
  const float* Wvo    = (const float*)d_in[30];
  const float* bvo    = (const float*)d_in[31];
  float* out = (float*)d_out;

  // workspace layout (all bf16 activations)
  unsigned short* xb      = (unsigned short*)d_ws;             // TOTN*64 bf16
  unsigned short* qkv     = xb + (size_t)TOTN*HD;              // TOTN*192 bf16
  unsigned short* attn_in = qkv + (size_t)TOTN*192;            // TOTN*64 bf16
  unsigned short* wpack   = attn_in + (size_t)TOTN*HD;         // 131072 bf16
  int* cnt     = (int*)(wpack + 131072);                       // TOTN
  int* rstart  = cnt + TOTN;
  int* cursor  = rstart + TOTN;
  int* esorted = cursor + TOTN;                                // TOTE
  // head partials (float) after the int region
  float* part1 = (float*)(esorted + TOTE);                     // 4*128*512
  float* part2 = part1 + 4*128*512;                            // 2*128*512
  float* partv = part2 + 2*128*512;                            // 8*128*128

  // weight prep + CSR build (edge topology is layer-invariant)
  k_wprep  <<<512, 256, 0, stream>>>(Wq, Wk, Wv, Wo, W1, W2, wpack);
  k_zero   <<<TOTN/256, 256, 0, stream>>>(cnt);
  k_hist   <<<TOTE/256, 256, 0, stream>>>(edst, cnt);
  k_scan   <<<GRAPHS, 1024, 0, stream>>>(cnt, rstart, cursor);
  k_scatter<<<TOTE/256, 256, 0, stream>>>(esrc, edst, cursor, esorted);

  k_in<<<TOTN/256, 256, 0, stream>>>(nf, Win, xb);
  for (int l=0; l<4; l++){
    const unsigned short* wl = wpack + l*32768;
    k_qkv_m   <<<TOTN/256, 256, 0, stream>>>(xb, wl, qkv);
    k_edge3   <<<TOTN/4, 256, 0, stream>>>(qkv, rstart, cnt, esorted, attn_in);
    k_attn_ffn<<<TOTN/256, 256, 0, stream>>>(attn_in, xb,
                                             wl + 12288,             // woT
                                             wl + 16384, b1 + l*128, // w1T, b1
                                             wl + 24576, b2 + l*64,  // w2T, b2
                                             ln1g + l*64, ln1b + l*64,
                                             ln2g + l*64, ln2b + l*64);
  }
  // policy head (3 dispatches)
  k_fc1   <<<dim3(2,64,4), 512, 0, stream>>>(xb, obs, agents, Wr, br, Wp1, part1);
  k_fc2   <<<dim3(2,64,2), 512, 0, stream>>>(part1, bp1, Wp2, part2);
  k_logits<<<GRAPHS, 256, 0, stream>>>(part2, bp2, Wlog, blog, out);
  // value head (2 dispatches)
  k_gemm_part<4,128,192,8,128><<<dim3(1,32,8), 512, 0, stream>>>(obs, 1500, 1500, Wv1, partv);
  k_vfin  <<<GRAPHS, 128, 0, stream>>>(partv, bv1, Wv2, bv2, Wvo, bvo, out);
}

// Round 15
// 486.429 us; speedup vs baseline: 1.1556x; 1.1556x over previous
//
#include <hip/hip_runtime.h>
#include <hip/hip_bf16.h>
#include <cstdint>
#include <cstddef>

#define DEV static __device__ __forceinline__

constexpr int GRAPHS = 128;
constexpr int NPG    = 1000;   // nodes per graph
constexpr int EPG    = 4000;   // edges per graph
constexpr int TOTN   = GRAPHS * NPG;  // 128000
constexpr int TOTE   = GRAPHS * EPG;  // 512000
constexpr int HD     = 64;
constexpr int OBSD   = 1500;
constexpr int AD     = 15;

typedef __attribute__((ext_vector_type(8))) short bf16x8;
typedef __attribute__((ext_vector_type(4))) float f32x4;

// ---------- helpers ----------
DEV unsigned short f2b(float f){   // round-to-nearest-even bf16
  unsigned u = __float_as_uint(f);
  return (unsigned short)((u + 0x7fffu + ((u >> 16) & 1u)) >> 16);
}
DEV float b2f(unsigned short s){ return __uint_as_float((unsigned)s << 16); }

DEV void fma4(float4& a, float s, const float4 w){
  a.x = fmaf(s, w.x, a.x); a.y = fmaf(s, w.y, a.y);
  a.z = fmaf(s, w.z, a.z); a.w = fmaf(s, w.w, a.w);
}

DEV ushort4 pack4(float4 v){
  ushort4 r; r.x=f2b(v.x); r.y=f2b(v.y); r.z=f2b(v.z); r.w=f2b(v.w); return r;
}

// ---------- weight prep: pack all layer weights to bf16 W^T ----------
// per layer (stride 32768 bf16): qkvT[192][64] | woT[64][64] | w1T[128][64] | w2T[64][128]
__global__ __launch_bounds__(256) void k_wprep(const float* __restrict__ Wq,
    const float* __restrict__ Wk, const float* __restrict__ Wv,
    const float* __restrict__ Wo, const float* __restrict__ W1,
    const float* __restrict__ W2, unsigned short* __restrict__ wpack){
  int e = blockIdx.x*256 + threadIdx.x;
  int l = e >> 15;
  int r = e & 32767;
  float val;
  if (r < 12288){
    int c = r >> 6, k = r & 63;
    val = (c < 64)  ? Wq[l*4096 + k*64 + c]
        : (c < 128) ? Wk[l*4096 + k*64 + (c-64)]
                    : Wv[l*4096 + k*64 + (c-128)];
  } else if (r < 16384){
    int i = r - 12288; int c = i >> 6, k = i & 63;
    val = Wo[l*4096 + k*64 + c];
  } else if (r < 24576){
    int i = r - 16384; int c = i >> 6, k = i & 63;
    val = W1[l*8192 + k*128 + c];
  } else {
    int i = r - 24576; int c = i >> 7, k = i & 127;
    val = W2[l*8192 + k*64 + c];
  }
  wpack[e] = f2b(val);
}

// ---------- CSR build (once per call; reused by all 4 layers) ----------
__global__ __launch_bounds__(256) void k_zero(int* __restrict__ cnt){
  cnt[blockIdx.x*256 + threadIdx.x] = 0;
}

__global__ __launch_bounds__(256) void k_hist(const int* __restrict__ edst,
                                              int* __restrict__ cnt){
  int e = blockIdx.x*256 + threadIdx.x;
  atomicAdd(&cnt[edst[e]], 1);
}

__global__ __launch_bounds__(1024) void k_scan(const int* __restrict__ cnt,
    int* __restrict__ rstart, int* __restrict__ cursor){
  __shared__ int s[1024];
  const int g = blockIdx.x, tid = threadIdx.x;
  int v = (tid < NPG) ? cnt[g*NPG + tid] : 0;
  s[tid] = v;
  __syncthreads();
  #pragma unroll
  for (int off=1; off<1024; off<<=1){
    int t = (tid >= off) ? s[tid-off] : 0;
    __syncthreads();
    s[tid] += t;
    __syncthreads();
  }
  if (tid < NPG){
    int r = g*EPG + (s[tid] - v);
    rstart[g*NPG+tid] = r;
    cursor[g*NPG+tid] = r;
  }
}

__global__ __launch_bounds__(256) void k_scatter(const int* __restrict__ esrc,
    const int* __restrict__ edst, int* __restrict__ cursor,
    int* __restrict__ esorted){
  int e = blockIdx.x*256 + threadIdx.x;
  int pos = atomicAdd(&cursor[edst[e]], 1);
  esorted[pos] = esrc[e];
}

// ---------- K1: x(bf16) = node_feats @ W_in  [128000,32]x[32,64] ----------
__global__ __launch_bounds__(256) void k_in(const float* __restrict__ nf,
                                            const float* __restrict__ Win,
                                            unsigned short* __restrict__ xb){
  __shared__ float  s_nf[256*36];
  __shared__ float4 s_w[512];
  const int tid = threadIdx.x;
  const int node0 = blockIdx.x * 256;
  const float4* W4 = (const float4*)Win;
  s_w[tid] = W4[tid]; s_w[tid+256] = W4[tid+256];
  const float4* nf4 = (const float4*)nf;
  float4* snf4 = (float4*)s_nf;
  #pragma unroll
  for (int r=0;r<8;r++){
    int i = tid + 256*r; int n = i>>3, k4 = i&7;
    snf4[n*9 + k4] = nf4[(size_t)(node0+n)*8 + k4];
  }
  __syncthreads();
  const int ng = tid>>2, cg = tid&3;
  float4 acc[4][4];
  #pragma unroll
  for (int i=0;i<4;i++){ acc[i][0]=make_float4(0,0,0,0); acc[i][1]=make_float4(0,0,0,0);
                         acc[i][2]=make_float4(0,0,0,0); acc[i][3]=make_float4(0,0,0,0); }
  #pragma unroll 4
  for (int k=0;k<32;k++){
    float nv[4];
    #pragma unroll
    for (int i=0;i<4;i++) nv[i] = s_nf[(ng + 64*i)*36 + k];
    float4 w[4];
    #pragma unroll
    for (int j=0;j<4;j++) w[j] = s_w[k*16 + cg*4 + j];
    #pragma unroll
    for (int i=0;i<4;i++){
      #pragma unroll
      for (int j=0;j<4;j++) fma4(acc[i][j], nv[i], w[j]);
    }
  }
  ushort4* xb4 = (ushort4*)xb;
  #pragma unroll
  for (int i=0;i<4;i++){
    size_t nidx = (size_t)(node0 + ng + 64*i) * 16;
    #pragma unroll
    for (int j=0;j<4;j++) xb4[nidx + cg*4 + j] = pack4(acc[i][j]);
  }
}

// ---------- K2 (MFMA): qkv(bf16) = x @ [Wq|Wk|Wv], 256 nodes/block ----------
__global__ __launch_bounds__(256) void k_qkv_m(const unsigned short* __restrict__ xb,
    const unsigned short* __restrict__ wqkvT,   // [192][64] bf16
    unsigned short* __restrict__ qkv){
  __shared__ short s_w[192*72];        // 27.6KB
  __shared__ short s_st[4][16*104];    // 13.3KB; pitch 104 (208B, 16B-aligned)
  const int tid = threadIdx.x;
  const int node0 = blockIdx.x * 256;
  {
    const unsigned* src = (const unsigned*)wqkvT;
    unsigned* dst = (unsigned*)s_w;
    #pragma unroll
    for (int r=0;r<24;r++){
      int j = tid + 256*r;
      int c = j >> 5, kk = j & 31;
      dst[c*36 + kk] = src[j];
    }
  }
  __syncthreads();
  const int lane = tid & 63, wave = tid >> 6;
  const int m = lane & 15, quad = lane >> 4;
  const int rowbase = node0 + wave*64;
  bf16x8 af[4][2];
  #pragma unroll
  for (int rt=0;rt<4;rt++){
    const unsigned short* xp = xb + (size_t)(rowbase + rt*16 + m)*64 + quad*8;
    af[rt][0] = *(const bf16x8*)xp;
    af[rt][1] = *(const bf16x8*)(xp + 32);
  }
  short* st = s_st[wave];
  #pragma unroll
  for (int rt=0;rt<4;rt++){
    #pragma unroll
    for (int half=0; half<2; half++){
      #pragma unroll
      for (int c6=0;c6<6;c6++){
        int ct = half*6 + c6;
        bf16x8 b0 = *(const bf16x8*)&s_w[(ct*16+m)*72 + quad*8];
        bf16x8 b1 = *(const bf16x8*)&s_w[(ct*16+m)*72 + 32 + quad*8];
        f32x4 acc = {0.f,0.f,0.f,0.f};
        acc = __builtin_amdgcn_mfma_f32_16x16x32_bf16(af[rt][0], b0, acc, 0,0,0);
        acc = __builtin_amdgcn_mfma_f32_16x16x32_bf16(af[rt][1], b1, acc, 0,0,0);
        #pragma unroll
        for (int i=0;i<4;i++)
          st[(quad*4+i)*104 + c6*16 + m] = (short)f2b(acc[i]);
      }
      // coalesced writeout of this 16x96 half-tile
      #pragma unroll
      for (int j=0;j<3;j++){
        int flat = (j*64 + lane)*8;
        int r = flat / 96, c = flat % 96;
        bf16x8 v = *(const bf16x8*)&st[r*104 + c];
        *(bf16x8*)(qkv + (size_t)(rowbase + rt*16 + r)*192 + half*96 + c) = v;
      }
    }
  }
}

// ---------- K4: edge attention via CSR gather; XCD-swizzled ----------
// Indices preloaded across dim-lanes (one esorted load per lane, covers n<=16)
// -> in-loop index comes from register shfl; k/v prefetched 2-deep.
__global__ __launch_bounds__(256) void k_edge2(const unsigned short* __restrict__ qkv,
    const int* __restrict__ rstart, const int* __restrict__ cnt,
    const int* __restrict__ esorted, unsigned short* __restrict__ attn_in){
  const int tid = threadIdx.x;
  const int wb = (blockIdx.x & 7)*1000 + (blockIdx.x >> 3);
  const int lane = tid & 63;
  const int sub  = lane >> 4;
  const int dg   = lane & 15;
  const int wave = tid >> 6;
  const int node = wb*16 + wave*4 + sub;
  ushort4 qu = *(const ushort4*)(qkv + (size_t)node*192 + dg*4);
  float q0 = b2f(qu.x), q1 = b2f(qu.y), q2 = b2f(qu.z), q3 = b2f(qu.w);
  const int rs = rstart[node];
  const int n  = cnt[node];
  const int nn = min(n, 16);
  // preload up to 16 neighbor indices (one per dim-lane)
  int myidx = (dg < nn) ? esorted[rs + dg] : node;
  const int lbase = lane & 48;      // first lane of this sub-node's group
  float a0=0.f, a1=0.f, a2=0.f, a3=0.f, den=0.f;
  ushort4 kA, vA, kB, vB;
  if (nn > 0){
    int s0 = __shfl(myidx, lbase);
    kA = *(const ushort4*)(qkv + (size_t)s0*192 + 64 + dg*4);
    vA = *(const ushort4*)(qkv + (size_t)s0*192 + 128 + dg*4);
  }
  if (nn > 1){
    int s1 = __shfl(myidx, lbase + 1);
    kB = *(const ushort4*)(qkv + (size_t)s1*192 + 64 + dg*4);
    vB = *(const ushort4*)(qkv + (size_t)s1*192 + 128 + dg*4);
  }
  for (int i=0;i<nn;i++){
    ushort4 ck = kA, cv = vA;
    kA = kB; vA = vB;
    if (i+2 < nn){
      int s2 = __shfl(myidx, lbase + i + 2);
      kB = *(const ushort4*)(qkv + (size_t)s2*192 + 64 + dg*4);
      vB = *(const ushort4*)(qkv + (size_t)s2*192 + 128 + dg*4);
    }
    float p = q0*b2f(ck.x) + q1*b2f(ck.y) + q2*b2f(ck.z) + q3*b2f(ck.w);
    p += __shfl_xor(p, 1);
    p += __shfl_xor(p, 2);          // sum over the 4 lanes of this head
    float w = __expf(p * 0.25f);    // softmax shift-invariant; skip segment_max
    den += w;
    a0 = fmaf(w, b2f(cv.x), a0);
    a1 = fmaf(w, b2f(cv.y), a1);
    a2 = fmaf(w, b2f(cv.z), a2);
    a3 = fmaf(w, b2f(cv.w), a3);
  }
  // rare tail: nodes with degree > 16 (P ~ 1e-6 per node)
  for (int i=16;i<n;i++){
    int src = esorted[rs + i];
    ushort4 ku = *(const ushort4*)(qkv + (size_t)src*192 + 64 + dg*4);
    ushort4 vu = *(const ushort4*)(qkv + (size_t)src*192 + 128 + dg*4);
    float p = q0*b2f(ku.x) + q1*b2f(ku.y) + q2*b2f(ku.z) + q3*b2f(ku.w);
    p += __shfl_xor(p, 1);
    p += __shfl_xor(p, 2);
    float w = __expf(p * 0.25f);
    den += w;
    a0 = fmaf(w, b2f(vu.x), a0);
    a1 = fmaf(w, b2f(vu.y), a1);
    a2 = fmaf(w, b2f(vu.z), a2);
    a3 = fmaf(w, b2f(vu.w), a3);
  }
  float inv = 1.0f/(den + 1e-9f);
  ushort4 o;
  o.x = f2b(a0*inv); o.y = f2b(a1*inv); o.z = f2b(a2*inv); o.w = f2b(a3*inv);
  ((ushort4*)attn_in)[(size_t)node*16 + dg] = o;
}

// ---------- K5 (MFMA): fused attn-proj + LN1 + ffn + LN2, 256 nodes/block ----
// LDS = 18432 + 17408 + 17408 = 53.2 KB -> 3 blocks/CU.
__global__ __launch_bounds__(256) void k_attn_ffn(
    const unsigned short* __restrict__ attn_in,
    unsigned short* __restrict__ xb,
    const unsigned short* __restrict__ woT,    // [64][64]
    const unsigned short* __restrict__ w1T, const float* __restrict__ b1_l,
    const unsigned short* __restrict__ w2T, const float* __restrict__ b2_l,
    const float* __restrict__ l1g, const float* __restrict__ l1b,
    const float* __restrict__ l2g, const float* __restrict__ l2b){
  __shared__ short s_w1[128*72];      // 18.4KB
  __shared__ short s_w2[64*136];      // 17.4KB
  __shared__ short s_st[4][16*136];   // 17.4KB per-wave stage (x1 then h then out)
  const int tid = threadIdx.x;
  const int node0 = blockIdx.x*256;
  {
    const unsigned* src = (const unsigned*)w1T;
    unsigned* dst = (unsigned*)s_w1;
    #pragma unroll
    for (int r=0;r<16;r++){
      int j = tid + 256*r;
      int c = j >> 5, kk = j & 31;
      dst[c*36 + kk] = src[j];
    }
  }
  {
    const unsigned* src = (const unsigned*)w2T;
    unsigned* dst = (unsigned*)s_w2;
    #pragma unroll
    for (int r=0;r<16;r++){
      int j = tid + 256*r;
      int c = j >> 6, kk = j & 63;
      dst[c*68 + kk] = src[j];
    }
  }
  const int lane = tid&63, wave = tid>>6;
  const int m = lane&15, quad = lane>>4;
  const int rowbase = node0 + wave*64;
  bf16x8 wo[4][2];
  #pragma unroll
  for (int ct=0;ct<4;ct++){
    wo[ct][0] = *(const bf16x8*)&woT[(ct*16+m)*64 + quad*8];
    wo[ct][1] = *(const bf16x8*)&woT[(ct*16+m)*64 + 32 + quad*8];
  }
  float g1[4], bb1[4], g2[4], bb2[4], b2v[4];
  #pragma unroll
  for (int ct=0;ct<4;ct++){
    g1[ct]=l1g[ct*16+m]; bb1[ct]=l1b[ct*16+m];
    g2[ct]=l2g[ct*16+m]; bb2[ct]=l2b[ct*16+m];
    b2v[ct]=b2_l[ct*16+m];
  }
  float b1v[8];
  #pragma unroll
  for (int ct=0;ct<8;ct++) b1v[ct]=b1_l[ct*16+m];
  bf16x8 af[4][2];
  #pragma unroll
  for (int rt=0;rt<4;rt++){
    const unsigned short* ap = attn_in + (size_t)(rowbase + rt*16 + m)*64 + quad*8;
    af[rt][0] = *(const bf16x8*)ap;
    af[rt][1] = *(const bf16x8*)(ap + 32);
  }
  __syncthreads();
  short* st = s_st[wave];
  #pragma unroll
  for (int rt=0;rt<4;rt++){
    // ---- attn projection ----
    f32x4 acc[4];
    #pragma unroll
    for (int ct=0;ct<4;ct++){
      f32x4 z = {0.f,0.f,0.f,0.f};
      z = __builtin_amdgcn_mfma_f32_16x16x32_bf16(af[rt][0], wo[ct][0], z, 0,0,0);
      z = __builtin_amdgcn_mfma_f32_16x16x32_bf16(af[rt][1], wo[ct][1], z, 0,0,0);
      acc[ct] = z;
    }
    // ---- residual + LN1 -> x1 (registers, C-layout) + stage cols 0..63 ----
    float x1v[4][4];
    #pragma unroll
    for (int i=0;i<4;i++){
      size_t row = (size_t)(rowbase + rt*16 + quad*4 + i)*64;
      float v0 = acc[0][i] + b2f(xb[row + m]);
      float v1 = acc[1][i] + b2f(xb[row + 16 + m]);
      float v2 = acc[2][i] + b2f(xb[row + 32 + m]);
      float v3 = acc[3][i] + b2f(xb[row + 48 + m]);
      float sm = v0+v1+v2+v3;
      float sq = v0*v0+v1*v1+v2*v2+v3*v3;
      #pragma unroll
      for (int mk=1; mk<16; mk<<=1){ sm += __shfl_xor(sm, mk); sq += __shfl_xor(sq, mk); }
      float mean = sm*0.015625f;
      float var  = sq*0.015625f - mean*mean;
      float rs   = rsqrtf(var + 1e-5f);
      x1v[i][0] = (v0-mean)*rs*g1[0]+bb1[0];
      x1v[i][1] = (v1-mean)*rs*g1[1]+bb1[1];
      x1v[i][2] = (v2-mean)*rs*g1[2]+bb1[2];
      x1v[i][3] = (v3-mean)*rs*g1[3]+bb1[3];
      int rl = quad*4 + i;
      st[rl*136 + m]      = (short)f2b(x1v[i][0]);
      st[rl*136 + 16 + m] = (short)f2b(x1v[i][1]);
      st[rl*136 + 32 + m] = (short)f2b(x1v[i][2]);
      st[rl*136 + 48 + m] = (short)f2b(x1v[i][3]);
    }
    // ---- ffn1 A-frags from stage ----
    bf16x8 x10 = *(const bf16x8*)&st[m*136 + quad*8];
    bf16x8 x11 = *(const bf16x8*)&st[m*136 + 32 + quad*8];
    // ---- ffn1: h = relu(x1@W1+b1) into stage ----
    #pragma unroll
    for (int ct=0;ct<8;ct++){
      bf16x8 b0 = *(const bf16x8*)&s_w1[(ct*16+m)*72 + quad*8];
      bf16x8 b1 = *(const bf16x8*)&s_w1[(ct*16+m)*72 + 32 + quad*8];
      f32x4 z = {0.f,0.f,0.f,0.f};
      z = __builtin_amdgcn_mfma_f32_16x16x32_bf16(x10, b0, z, 0,0,0);
      z = __builtin_amdgcn_mfma_f32_16x16x32_bf16(x11, b1, z, 0,0,0);
      #pragma unroll
      for (int i=0;i<4;i++)
        st[(quad*4+i)*136 + ct*16 + m] = (short)f2b(fmaxf(z[i]+b1v[ct], 0.f));
    }
    // ---- ffn2 ----
    bf16x8 h0 = *(const bf16x8*)&st[m*136 + quad*8];
    bf16x8 h1 = *(const bf16x8*)&st[m*136 + 32 + quad*8];
    bf16x8 h2 = *(const bf16x8*)&st[m*136 + 64 + quad*8];
    bf16x8 h3 = *(const bf16x8*)&st[m*136 + 96 + quad*8];
    f32x4 acc2[4];
    #pragma unroll
    for (int ct=0;ct<4;ct++){
      f32x4 z = {0.f,0.f,0.f,0.f};
      z = __builtin_amdgcn_mfma_f32_16x16x32_bf16(h0, *(const bf16x8*)&s_w2[(ct*16+m)*136 + quad*8],      z, 0,0,0);
      z = __builtin_amdgcn_mfma_f32_16x16x32_bf16(h1, *(const bf16x8*)&s_w2[(ct*16+m)*136 + 32 + quad*8], z, 0,0,0);
      z = __builtin_amdgcn_mfma_f32_16x16x32_bf16(h2, *(const bf16x8*)&s_w2[(ct*16+m)*136 + 64 + quad*8], z, 0,0,0);
      z = __builtin_amdgcn_mfma_f32_16x16x32_bf16(h3, *(const bf16x8*)&s_w2[(ct*16+m)*136 + 96 + quad*8], z, 0,0,0);
      acc2[ct] = z;
    }
    // ---- residual (x1 registers) + b2 + LN2 -> stage cols 0..63 ----
    #pragma unroll
    for (int i=0;i<4;i++){
      float v0 = acc2[0][i] + b2v[0] + x1v[i][0];
      float v1 = acc2[1][i] + b2v[1] + x1v[i][1];
      float v2 = acc2[2][i] + b2v[2] + x1v[i][2];
      float v3 = acc2[3][i] + b2v[3] + x1v[i][3];
      float sm = v0+v1+v2+v3;
      float sq = v0*v0+v1*v1+v2*v2+v3*v3;
      #pragma unroll
      for (int mk=1; mk<16; mk<<=1){ sm += __shfl_xor(sm, mk); sq += __shfl_xor(sq, mk); }
      float mean = sm*0.015625f;
      float var  = sq*0.015625f - mean*mean;
      float rs   = rsqrtf(var + 1e-5f);
      int rl = quad*4 + i;
      st[rl*136 + m]      = (short)f2b((v0-mean)*rs*g2[0]+bb2[0]);
      st[rl*136 + 16 + m] = (short)f2b((v1-mean)*rs*g2[1]+bb2[1]);
      st[rl*136 + 32 + m] = (short)f2b((v2-mean)*rs*g2[2]+bb2[2]);
      st[rl*136 + 48 + m] = (short)f2b((v3-mean)*rs*g2[3]+bb2[3]);
    }
    // ---- coalesced store of new x ----
    #pragma unroll
    for (int j=0;j<2;j++){
      int flat = (j*64 + lane)*8;
      int r = flat >> 6, c = flat & 63;
      bf16x8 v = *(const bf16x8*)&st[r*136 + c];
      *(bf16x8*)(xb + (size_t)(rowbase + rt*16 + r)*64 + c) = v;
    }
  }
}

// ---------- heads: FC1 with inline feat assembly (gat_out + obs) ----------
__global__ __launch_bounds__(512) void k_fc1(const unsigned short* __restrict__ xb,
    const float* __restrict__ obs, const int* __restrict__ agents,
    const float* __restrict__ Wr, const float* __restrict__ br,
    const float* __restrict__ Wp1, float* __restrict__ part1){
  constexpr int ROWS=2, COLS=256, CH=384, K=1515, N=512;
  const int chunk = 379;
  __shared__ float s_a[ROWS*CH];
  const int tid = threadIdx.x;
  const int ct = blockIdx.x, rg = blockIdx.y, ks = blockIdx.z;
  const int k0 = ks * chunk;
  const int len = min(K - k0, chunk);
  const int row0 = rg * ROWS;
  #pragma unroll
  for (int rr=0; rr<ROWS; rr++)
    for (int i=tid; i<len; i+=512){
      int k = k0 + i;
      if (k >= AD) s_a[rr*CH + i] = obs[(size_t)(row0+rr)*OBSD + (k-AD)];
    }
  if (ks==0 && tid < ROWS*AD){
    int rr = tid/AD, c = tid%AD;
    int b = row0 + rr;
    const unsigned short* xa = xb + (size_t)agents[b]*HD;
    float a = br[c];
    #pragma unroll 8
    for (int k=0;k<HD;k++) a = fmaf(b2f(xa[k]), Wr[k*AD + c], a);
    s_a[rr*CH + c] = a;
  }
  __syncthreads();
  const int r = tid / COLS, c = tid % COLS;
  const float* wp = Wp1 + (size_t)k0*N + ct*COLS + c;
  const float* ap = s_a + r*CH;
  float acc = 0.f;
  #pragma unroll 8
  for (int k=0;k<len;k++) acc = fmaf(ap[k], wp[(size_t)k*N], acc);
  part1[((size_t)ks*128 + row0 + r)*N + ct*COLS + c] = acc;
}

// ---------- heads: FC2 with reduce+tanh on A-load ----------
__global__ __launch_bounds__(512) void k_fc2(const float* __restrict__ part1,
    const float* __restrict__ bp1, const float* __restrict__ Wp2,
    float* __restrict__ part2){
  constexpr int ROWS=2, COLS=256, CH=256, N=512;
  __shared__ float s_a[ROWS*CH];
  const int tid = threadIdx.x;
  const int ct = blockIdx.x, rg = blockIdx.y, ks = blockIdx.z;
  const int k0 = ks * CH;
  const int row0 = rg * ROWS;
  #pragma unroll
  for (int rr=0; rr<ROWS; rr++)
    for (int i=tid; i<CH; i+=512){
      int k = k0 + i;
      float s = bp1[k];
      #pragma unroll
      for (int j=0;j<4;j++) s += part1[((size_t)j*128 + row0+rr)*512 + k];
      s_a[rr*CH + i] = tanhf(s);
    }
  __syncthreads();
  const int r = tid / COLS, c = tid % COLS;
  const float* wp = Wp2 + (size_t)k0*N + ct*COLS + c;
  const float* ap = s_a + r*CH;
  float acc = 0.f;
  #pragma unroll 8
  for (int k=0;k<CH;k++) acc = fmaf(ap[k], wp[(size_t)k*N], acc);
  part2[((size_t)ks*128 + row0 + r)*N + ct*COLS + c] = acc;
}

// ---------- heads: logits with reduce+tanh on load ----------
__global__ __launch_bounds__(256) void k_logits(const float* __restrict__ part2,
    const float* __restrict__ bp2, const float* __restrict__ Wlog,
    const float* __restrict__ blog, float* __restrict__ out){
  __shared__ float s_f[512];
  __shared__ float s_p[16*AD];
  const int b = blockIdx.x, tid = threadIdx.x;
  for (int i=tid;i<512;i+=256){
    float s = bp2[i] + part2[(size_t)b*512 + i] + part2[(size_t)(128+b)*512 + i];
    s_f[i] = tanhf(s);
  }
  __syncthreads();
  if (tid < 240){
    int c = tid % AD, kc = tid / AD;
    float a = 0.f;
    #pragma unroll 8
    for (int j=0;j<32;j++){ int k = kc*32 + j; a = fmaf(s_f[k], Wlog[k*AD + c], a); }
    s_p[tid] = a;
  }
  __syncthreads();
  if (tid < AD){
    float a = blog[tid];
    #pragma unroll
    for (int kc=0;kc<16;kc++) a += s_p[kc*AD + tid];
    out[(size_t)b*AD + tid] = a;
  }
}

// ---------- heads: value split-K GEMM ----------
template<int ROWS, int COLS, int CH, int KS, int N>
__global__ __launch_bounds__(ROWS*COLS) void k_gemm_part(
    const float* __restrict__ A, int lda, int K,
    const float* __restrict__ W, float* __restrict__ part){
  constexpr int BT = ROWS*COLS;
  __shared__ float s_a[ROWS*CH];
  const int tid = threadIdx.x;
  const int ct = blockIdx.x, rg = blockIdx.y, ks = blockIdx.z;
  const int chunk = (K + KS - 1) / KS;
  const int k0 = ks * chunk;
  const int len = min(K - k0, chunk);
  const int row0 = rg * ROWS;
  #pragma unroll
  for (int rr=0; rr<ROWS; rr++)
    for (int i=tid; i<len; i+=BT)
      s_a[rr*CH + i] = A[(size_t)(row0+rr)*lda + k0 + i];
  __syncthreads();
  const int r = tid / COLS, c = tid % COLS;
  const float* wp = W + (size_t)k0*N + ct*COLS + c;
  const float* ap = s_a + r*CH;
  float acc = 0.f;
  #pragma unroll 8
  for (int k=0;k<len;k++) acc = fmaf(ap[k], wp[(size_t)k*N], acc);
  part[((size_t)ks*128 + row0 + r)*N + ct*COLS + c] = acc;
}

// ---------- heads: value finish with reduce+tanh on load ----------
__global__ __launch_bounds__(128) void k_vfin(const float* __restrict__ partv,
    const float* __restrict__ bv1, const float* __restrict__ Wv2,
    const float* __restrict__ bv2, const float* __restrict__ Wvo,
    const float* __restrict__ bvo, float* __restrict__ out){
  __shared__ float s_v[128];
  __shared__ float s_r[128];
  const int b = blockIdx.x, tid = threadIdx.x;
  {
    float s = bv1[tid];
    #pragma unroll
    for (int j=0;j<8;j++) s += partv[((size_t)j*128 + b)*128 + tid];
    s_v[tid] = tanhf(s);
  }
  __syncthreads();
  float a = bv2[tid];
  #pragma unroll 8
  for (int k=0;k<128;k++) a = fmaf(s_v[k], Wv2[k*128 + tid], a);
  s_r[tid] = tanhf(a) * Wvo[tid];
  __syncthreads();
  if (tid < 64){
    float v = s_r[tid] + s_r[tid+64];
    #pragma unroll
    for (int m=32;m>=1;m>>=1) v += __shfl_xor(v, m);
    if (tid==0) out[GRAPHS*AD + b] = v + bvo[0];
  }
}

// ---------- launch ----------
extern "C" void kernel_launch(void* const* d_in, const int* in_sizes, int n_in,
                              void* d_out, int out_size, void* d_ws, size_t ws_size,
                              hipStream_t stream) {
  (void)in_sizes; (void)n_in; (void)out_size; (void)ws_size;
  const float* nf     = (const float*)d_in[0];
  const float* obs    = (const float*)d_in[1];
  const int*   esrc   = (const int*)d_in[2];
  const int*   edst   = (const int*)d_in[3];
  const int*   agents = (const int*)d_in[4];
  const float* Win    = (const float*)d_in[5];
  const float* Wq     = (const float*)d_in[6];
  const float* Wk     = (const float*)d_in[7];
  const float* Wv     = (const float*)d_in[8];
  const float* Wo     = (const float*)d_in[9];
  const float* ln1g   = (const float*)d_in[10];
  const float* ln1b   = (const float*)d_in[11];
  const float* W1     = (const float*)d_in[12];
  const float* b1     = (const float*)d_in[13];
  const float* W2     = (const float*)d_in[14];
  const float* b2     = (const float*)d_in[15];
  const float* ln2g   = (const float*)d_in[16];
  const float* ln2b   = (const float*)d_in[17];
  const float* Wr     = (const float*)d_in[18];
  const float* br     = (const float*)d_in[19];
  const float* Wp1    = (const float*)d_in[20];
  const float* bp1    = (const float*)d_in[21];
  const float* Wp2    = (const float*)d_in[22];
  const float* bp2    = (const float*)d_in[23];
  const float* Wlog   = (const float*)d_in[24];
  const float* blog   = (const float*)d_in[25];
  const float* Wv1    = (const float*)d_in[26];
  const float* bv1    = (const float*)d_in[27];
  const float* Wv2    = (const float*)d_in[28];
  const float* bv2    = (const float*)d_in[29];
  const float* Wvo    = (const float*)d_in[30];
  const float* bvo    = (const float*)d_in[31];
  float* out = (float*)d_out;

  // workspace layout (all bf16 activations)
  unsigned short* xb      = (unsigned short*)d_ws;             // TOTN*64 bf16
  unsigned short* qkv     = xb + (size_t)TOTN*HD;              // TOTN*192 bf16
  unsigned short* attn_in = qkv + (size_t)TOTN*192;            // TOTN*64 bf16
  unsigned short* wpack   = attn_in + (size_t)TOTN*HD;         // 131072 bf16
  int* cnt     = (int*)(wpack + 131072);                       // TOTN
  int* rstart  = cnt + TOTN;
  int* cursor  = rstart + TOTN;
  int* esorted = cursor + TOTN;                                // TOTE
  // head partials (float) after the int region
  float* part1 = (float*)(esorted + TOTE);                     // 4*128*512
  float* part2 = part1 + 4*128*512;                            // 2*128*512
  float* partv = part2 + 2*128*512;                            // 8*128*128

  // weight prep + CSR build (edge topology is layer-invariant)
  k_wprep  <<<512, 256, 0, stream>>>(Wq, Wk, Wv, Wo, W1, W2, wpack);
  k_zero   <<<TOTN/256, 256, 0, stream>>>(cnt);
  k_hist   <<<TOTE/256, 256, 0, stream>>>(edst, cnt);
  k_scan   <<<GRAPHS, 1024, 0, stream>>>(cnt, rstart, cursor);
  k_scatter<<<TOTE/256, 256, 0, stream>>>(esrc, edst, cursor, esorted);

  k_in<<<TOTN/256, 256, 0, stream>>>(nf, Win, xb);
  for (int l=0; l<4; l++){
    const unsigned short* wl = wpack + l*32768;
    k_qkv_m   <<<TOTN/256, 256, 0, stream>>>(xb, wl, qkv);
    k_edge2   <<<TOTN/16, 256, 0, stream>>>(qkv, rstart, cnt, esorted, attn_in);
    k_attn_ffn<<<TOTN/256, 256, 0, stream>>>(attn_in, xb,
                                             wl + 12288,             // woT
                                             wl + 16384, b1 + l*128, // w1T, b1
                                             wl + 24576, b2 + l*64,  // w2T, b2
                                             ln1g + l*64, ln1b + l*64,
                                             ln2g + l*64, ln2b + l*64);
  }
  // policy head (3 dispatches)
  k_fc1   <<<dim3(2,64,4), 512, 0, stream>>>(xb, obs, agents, Wr, br, Wp1, part1);
  k_fc2   <<<dim3(2,64,2), 512, 0, stream>>>(part1, bp1, Wp2, part2);
  k_logits<<<GRAPHS, 256, 0, stream>>>(part2, bp2, Wlog, blog, out);
  // value head (2 dispatches)
  k_gemm_part<4,128,192,8,128><<<dim3(1,32,8), 512, 0, stream>>>(obs, 1500, 1500, Wv1, partv);
  k_vfin  <<<GRAPHS, 128, 0, stream>>>(partv, bv1, Wv2, bv2, Wvo, bvo, out);
}

// Round 16
// 483.387 us; speedup vs baseline: 1.1629x; 1.0063x over previous
//
#include <hip/hip_runtime.h>
#include <hip/hip_bf16.h>
#include <cstdint>
#include <cstddef>

#define DEV static __device__ __forceinline__

constexpr int GRAPHS = 128;
constexpr int NPG    = 1000;   // nodes per graph
constexpr int EPG    = 4000;   // edges per graph
constexpr int TOTN   = GRAPHS * NPG;  // 128000
constexpr int TOTE   = GRAPHS * EPG;  // 512000
constexpr int HD     = 64;
constexpr int OBSD   = 1500;
constexpr int AD     = 15;

typedef __attribute__((ext_vector_type(8))) short bf16x8;
typedef __attribute__((ext_vector_type(4))) float f32x4;

// ---------- helpers ----------
DEV unsigned short f2b(float f){   // round-to-nearest-even bf16
  unsigned u = __float_as_uint(f);
  return (unsigned short)((u + 0x7fffu + ((u >> 16) & 1u)) >> 16);
}
DEV float b2f(unsigned short s){ return __uint_as_float((unsigned)s << 16); }

DEV void fma4(float4& a, float s, const float4 w){
  a.x = fmaf(s, w.x, a.x); a.y = fmaf(s, w.y, a.y);
  a.z = fmaf(s, w.z, a.z); a.w = fmaf(s, w.w, a.w);
}

DEV ushort4 pack4(float4 v){
  ushort4 r; r.x=f2b(v.x); r.y=f2b(v.y); r.z=f2b(v.z); r.w=f2b(v.w); return r;
}

// ---------- weight prep: pack all layer weights to bf16 W^T ----------
// per layer (stride 32768 bf16): qkvT[192][64] | woT[64][64] | w1T[128][64] | w2T[64][128]
__global__ __launch_bounds__(256) void k_wprep(const float* __restrict__ Wq,
    const float* __restrict__ Wk, const float* __restrict__ Wv,
    const float* __restrict__ Wo, const float* __restrict__ W1,
    const float* __restrict__ W2, unsigned short* __restrict__ wpack){
  int e = blockIdx.x*256 + threadIdx.x;
  int l = e >> 15;
  int r = e & 32767;
  float val;
  if (r < 12288){
    int c = r >> 6, k = r & 63;
    val = (c < 64)  ? Wq[l*4096 + k*64 + c]
        : (c < 128) ? Wk[l*4096 + k*64 + (c-64)]
                    : Wv[l*4096 + k*64 + (c-128)];
  } else if (r < 16384){
    int i = r - 12288; int c = i >> 6, k = i & 63;
    val = Wo[l*4096 + k*64 + c];
  } else if (r < 24576){
    int i = r - 16384; int c = i >> 6, k = i & 63;
    val = W1[l*8192 + k*128 + c];
  } else {
    int i = r - 24576; int c = i >> 7, k = i & 127;
    val = W2[l*8192 + k*64 + c];
  }
  wpack[e] = f2b(val);
}

// ---------- CSR build (once per call; reused by all 4 layers) ----------
__global__ __launch_bounds__(256) void k_zero(int* __restrict__ cnt){
  cnt[blockIdx.x*256 + threadIdx.x] = 0;
}

__global__ __launch_bounds__(256) void k_hist(const int* __restrict__ edst,
                                              int* __restrict__ cnt){
  int e = blockIdx.x*256 + threadIdx.x;
  atomicAdd(&cnt[edst[e]], 1);
}

__global__ __launch_bounds__(1024) void k_scan(const int* __restrict__ cnt,
    int* __restrict__ rstart, int* __restrict__ cursor){
  __shared__ int s[1024];
  const int g = blockIdx.x, tid = threadIdx.x;
  int v = (tid < NPG) ? cnt[g*NPG + tid] : 0;
  s[tid] = v;
  __syncthreads();
  #pragma unroll
  for (int off=1; off<1024; off<<=1){
    int t = (tid >= off) ? s[tid-off] : 0;
    __syncthreads();
    s[tid] += t;
    __syncthreads();
  }
  if (tid < NPG){
    int r = g*EPG + (s[tid] - v);
    rstart[g*NPG+tid] = r;
    cursor[g*NPG+tid] = r;
  }
}

__global__ __launch_bounds__(256) void k_scatter(const int* __restrict__ esrc,
    const int* __restrict__ edst, int* __restrict__ cursor,
    int* __restrict__ esorted){
  int e = blockIdx.x*256 + threadIdx.x;
  int pos = atomicAdd(&cursor[edst[e]], 1);
  esorted[pos] = esrc[e];
}

// ---------- K1: x(bf16) = node_feats @ W_in  [128000,32]x[32,64] ----------
__global__ __launch_bounds__(256) void k_in(const float* __restrict__ nf,
                                            const float* __restrict__ Win,
                                            unsigned short* __restrict__ xb){
  __shared__ float  s_nf[256*36];
  __shared__ float4 s_w[512];
  const int tid = threadIdx.x;
  const int node0 = blockIdx.x * 256;
  const float4* W4 = (const float4*)Win;
  s_w[tid] = W4[tid]; s_w[tid+256] = W4[tid+256];
  const float4* nf4 = (const float4*)nf;
  float4* snf4 = (float4*)s_nf;
  #pragma unroll
  for (int r=0;r<8;r++){
    int i = tid + 256*r; int n = i>>3, k4 = i&7;
    snf4[n*9 + k4] = nf4[(size_t)(node0+n)*8 + k4];
  }
  __syncthreads();
  const int ng = tid>>2, cg = tid&3;
  float4 acc[4][4];
  #pragma unroll
  for (int i=0;i<4;i++){ acc[i][0]=make_float4(0,0,0,0); acc[i][1]=make_float4(0,0,0,0);
                         acc[i][2]=make_float4(0,0,0,0); acc[i][3]=make_float4(0,0,0,0); }
  #pragma unroll 4
  for (int k=0;k<32;k++){
    float nv[4];
    #pragma unroll
    for (int i=0;i<4;i++) nv[i] = s_nf[(ng + 64*i)*36 + k];
    float4 w[4];
    #pragma unroll
    for (int j=0;j<4;j++) w[j] = s_w[k*16 + cg*4 + j];
    #pragma unroll
    for (int i=0;i<4;i++){
      #pragma unroll
      for (int j=0;j<4;j++) fma4(acc[i][j], nv[i], w[j]);
    }
  }
  ushort4* xb4 = (ushort4*)xb;
  #pragma unroll
  for (int i=0;i<4;i++){
    size_t nidx = (size_t)(node0 + ng + 64*i) * 16;
    #pragma unroll
    for (int j=0;j<4;j++) xb4[nidx + cg*4 + j] = pack4(acc[i][j]);
  }
}

// ---------- K2 (MFMA): qkv(bf16) = x @ [Wq|Wk|Wv] — layer 0 only ----------
__global__ __launch_bounds__(256) void k_qkv_m(const unsigned short* __restrict__ xb,
    const unsigned short* __restrict__ wqkvT,   // [192][64] bf16
    unsigned short* __restrict__ qkv){
  __shared__ short s_w[192*72];        // 27.6KB
  __shared__ short s_st[4][16*104];    // 13.3KB; pitch 104 (208B, 16B-aligned)
  const int tid = threadIdx.x;
  const int node0 = blockIdx.x * 256;
  {
    const unsigned* src = (const unsigned*)wqkvT;
    unsigned* dst = (unsigned*)s_w;
    #pragma unroll
    for (int r=0;r<24;r++){
      int j = tid + 256*r;
      int c = j >> 5, kk = j & 31;
      dst[c*36 + kk] = src[j];
    }
  }
  __syncthreads();
  const int lane = tid & 63, wave = tid >> 6;
  const int m = lane & 15, quad = lane >> 4;
  const int rowbase = node0 + wave*64;
  bf16x8 af[4][2];
  #pragma unroll
  for (int rt=0;rt<4;rt++){
    const unsigned short* xp = xb + (size_t)(rowbase + rt*16 + m)*64 + quad*8;
    af[rt][0] = *(const bf16x8*)xp;
    af[rt][1] = *(const bf16x8*)(xp + 32);
  }
  short* st = s_st[wave];
  #pragma unroll
  for (int rt=0;rt<4;rt++){
    #pragma unroll
    for (int half=0; half<2; half++){
      #pragma unroll
      for (int c6=0;c6<6;c6++){
        int ct = half*6 + c6;
        bf16x8 b0 = *(const bf16x8*)&s_w[(ct*16+m)*72 + quad*8];
        bf16x8 b1 = *(const bf16x8*)&s_w[(ct*16+m)*72 + 32 + quad*8];
        f32x4 acc = {0.f,0.f,0.f,0.f};
        acc = __builtin_amdgcn_mfma_f32_16x16x32_bf16(af[rt][0], b0, acc, 0,0,0);
        acc = __builtin_amdgcn_mfma_f32_16x16x32_bf16(af[rt][1], b1, acc, 0,0,0);
        #pragma unroll
        for (int i=0;i<4;i++)
          st[(quad*4+i)*104 + c6*16 + m] = (short)f2b(acc[i]);
      }
      // coalesced writeout of this 16x96 half-tile
      #pragma unroll
      for (int j=0;j<3;j++){
        int flat = (j*64 + lane)*8;
        int r = flat / 96, c = flat % 96;
        bf16x8 v = *(const bf16x8*)&st[r*104 + c];
        *(bf16x8*)(qkv + (size_t)(rowbase + rt*16 + r)*192 + half*96 + c) = v;
      }
    }
  }
}

// ---------- K4: edge attention via CSR gather; XCD-swizzled ----------
// Indices preloaded across dim-lanes (one esorted load per lane, covers n<=16)
// -> in-loop index comes from register shfl; k/v prefetched 2-deep.
__global__ __launch_bounds__(256) void k_edge2(const unsigned short* __restrict__ qkv,
    const int* __restrict__ rstart, const int* __restrict__ cnt,
    const int* __restrict__ esorted, unsigned short* __restrict__ attn_in){
  const int tid = threadIdx.x;
  const int wb = (blockIdx.x & 7)*1000 + (blockIdx.x >> 3);
  const int lane = tid & 63;
  const int sub  = lane >> 4;
  const int dg   = lane & 15;
  const int wave = tid >> 6;
  const int node = wb*16 + wave*4 + sub;
  ushort4 qu = *(const ushort4*)(qkv + (size_t)node*192 + dg*4);
  float q0 = b2f(qu.x), q1 = b2f(qu.y), q2 = b2f(qu.z), q3 = b2f(qu.w);
  const int rs = rstart[node];
  const int n  = cnt[node];
  const int nn = min(n, 16);
  int myidx = (dg < nn) ? esorted[rs + dg] : node;
  const int lbase = lane & 48;
  float a0=0.f, a1=0.f, a2=0.f, a3=0.f, den=0.f;
  ushort4 kA, vA, kB, vB;
  if (nn > 0){
    int s0 = __shfl(myidx, lbase);
    kA = *(const ushort4*)(qkv + (size_t)s0*192 + 64 + dg*4);
    vA = *(const ushort4*)(qkv + (size_t)s0*192 + 128 + dg*4);
  }
  if (nn > 1){
    int s1 = __shfl(myidx, lbase + 1);
    kB = *(const ushort4*)(qkv + (size_t)s1*192 + 64 + dg*4);
    vB = *(const ushort4*)(qkv + (size_t)s1*192 + 128 + dg*4);
  }
  for (int i=0;i<nn;i++){
    ushort4 ck = kA, cv = vA;
    kA = kB; vA = vB;
    if (i+2 < nn){
      int s2 = __shfl(myidx, lbase + i + 2);
      kB = *(const ushort4*)(qkv + (size_t)s2*192 + 64 + dg*4);
      vB = *(const ushort4*)(qkv + (size_t)s2*192 + 128 + dg*4);
    }
    float p = q0*b2f(ck.x) + q1*b2f(ck.y) + q2*b2f(ck.z) + q3*b2f(ck.w);
    p += __shfl_xor(p, 1);
    p += __shfl_xor(p, 2);          // sum over the 4 lanes of this head
    float w = __expf(p * 0.25f);    // softmax shift-invariant; skip segment_max
    den += w;
    a0 = fmaf(w, b2f(cv.x), a0);
    a1 = fmaf(w, b2f(cv.y), a1);
    a2 = fmaf(w, b2f(cv.z), a2);
    a3 = fmaf(w, b2f(cv.w), a3);
  }
  // rare tail: nodes with degree > 16 (P ~ 1e-6 per node)
  for (int i=16;i<n;i++){
    int src = esorted[rs + i];
    ushort4 ku = *(const ushort4*)(qkv + (size_t)src*192 + 64 + dg*4);
    ushort4 vu = *(const ushort4*)(qkv + (size_t)src*192 + 128 + dg*4);
    float p = q0*b2f(ku.x) + q1*b2f(ku.y) + q2*b2f(ku.z) + q3*b2f(ku.w);
    p += __shfl_xor(p, 1);
    p += __shfl_xor(p, 2);
    float w = __expf(p * 0.25f);
    den += w;
    a0 = fmaf(w, b2f(vu.x), a0);
    a1 = fmaf(w, b2f(vu.y), a1);
    a2 = fmaf(w, b2f(vu.z), a2);
    a3 = fmaf(w, b2f(vu.w), a3);
  }
  float inv = 1.0f/(den + 1e-9f);
  ushort4 o;
  o.x = f2b(a0*inv); o.y = f2b(a1*inv); o.z = f2b(a2*inv); o.w = f2b(a3*inv);
  ((ushort4*)attn_in)[(size_t)node*16 + dg] = o;
}

// ---------- K5 (MFMA): fused attn-proj + LN1 + ffn + LN2 + next-layer qkv ----
// LDS = 18432 + 17408 + 17408 = 53.2 KB -> 3 blocks/CU.
// qkv B-frags read from global (L2-resident) like wo; x2 stays in the stage.
__global__ __launch_bounds__(256) void k_attn_ffn(
    const unsigned short* __restrict__ attn_in,
    unsigned short* __restrict__ xb,
    const unsigned short* __restrict__ woT,    // [64][64]
    const unsigned short* __restrict__ w1T, const float* __restrict__ b1_l,
    const unsigned short* __restrict__ w2T, const float* __restrict__ b2_l,
    const float* __restrict__ l1g, const float* __restrict__ l1b,
    const float* __restrict__ l2g, const float* __restrict__ l2b,
    const unsigned short* __restrict__ wqkvT,  // [192][64] next layer; null on last
    unsigned short* __restrict__ qkv){
  __shared__ short s_w1[128*72];      // 18.4KB
  __shared__ short s_w2[64*136];      // 17.4KB
  __shared__ short s_st[4][16*136];   // 17.4KB per-wave stage (x1/h/out/qkv)
  const int tid = threadIdx.x;
  const int node0 = blockIdx.x*256;
  {
    const unsigned* src = (const unsigned*)w1T;
    unsigned* dst = (unsigned*)s_w1;
    #pragma unroll
    for (int r=0;r<16;r++){
      int j = tid + 256*r;
      int c = j >> 5, kk = j & 31;
      dst[c*36 + kk] = src[j];
    }
  }
  {
    const unsigned* src = (const unsigned*)w2T;
    unsigned* dst = (unsigned*)s_w2;
    #pragma unroll
    for (int r=0;r<16;r++){
      int j = tid + 256*r;
      int c = j >> 6, kk = j & 63;
      dst[c*68 + kk] = src[j];
    }
  }
  const int lane = tid&63, wave = tid>>6;
  const int m = lane&15, quad = lane>>4;
  const int rowbase = node0 + wave*64;
  bf16x8 wo[4][2];
  #pragma unroll
  for (int ct=0;ct<4;ct++){
    wo[ct][0] = *(const bf16x8*)&woT[(ct*16+m)*64 + quad*8];
    wo[ct][1] = *(const bf16x8*)&woT[(ct*16+m)*64 + 32 + quad*8];
  }
  float g1[4], bb1[4], g2[4], bb2[4], b2v[4];
  #pragma unroll
  for (int ct=0;ct<4;ct++){
    g1[ct]=l1g[ct*16+m]; bb1[ct]=l1b[ct*16+m];
    g2[ct]=l2g[ct*16+m]; bb2[ct]=l2b[ct*16+m];
    b2v[ct]=b2_l[ct*16+m];
  }
  float b1v[8];
  #pragma unroll
  for (int ct=0;ct<8;ct++) b1v[ct]=b1_l[ct*16+m];
  bf16x8 af[4][2];
  #pragma unroll
  for (int rt=0;rt<4;rt++){
    const unsigned short* ap = attn_in + (size_t)(rowbase + rt*16 + m)*64 + quad*8;
    af[rt][0] = *(const bf16x8*)ap;
    af[rt][1] = *(const bf16x8*)(ap + 32);
  }
  __syncthreads();
  short* st = s_st[wave];
  #pragma unroll
  for (int rt=0;rt<4;rt++){
    // ---- attn projection ----
    f32x4 acc[4];
    #pragma unroll
    for (int ct=0;ct<4;ct++){
      f32x4 z = {0.f,0.f,0.f,0.f};
      z = __builtin_amdgcn_mfma_f32_16x16x32_bf16(af[rt][0], wo[ct][0], z, 0,0,0);
      z = __builtin_amdgcn_mfma_f32_16x16x32_bf16(af[rt][1], wo[ct][1], z, 0,0,0);
      acc[ct] = z;
    }
    // ---- residual + LN1 -> x1 (registers, C-layout) + stage cols 0..63 ----
    float x1v[4][4];
    #pragma unroll
    for (int i=0;i<4;i++){
      size_t row = (size_t)(rowbase + rt*16 + quad*4 + i)*64;
      float v0 = acc[0][i] + b2f(xb[row + m]);
      float v1 = acc[1][i] + b2f(xb[row + 16 + m]);
      float v2 = acc[2][i] + b2f(xb[row + 32 + m]);
      float v3 = acc[3][i] + b2f(xb[row + 48 + m]);
      float sm = v0+v1+v2+v3;
      float sq = v0*v0+v1*v1+v2*v2+v3*v3;
      #pragma unroll
      for (int mk=1; mk<16; mk<<=1){ sm += __shfl_xor(sm, mk); sq += __shfl_xor(sq, mk); }
      float mean = sm*0.015625f;
      float var  = sq*0.015625f - mean*mean;
      float rs   = rsqrtf(var + 1e-5f);
      x1v[i][0] = (v0-mean)*rs*g1[0]+bb1[0];
      x1v[i][1] = (v1-mean)*rs*g1[1]+bb1[1];
      x1v[i][2] = (v2-mean)*rs*g1[2]+bb1[2];
      x1v[i][3] = (v3-mean)*rs*g1[3]+bb1[3];
      int rl = quad*4 + i;
      st[rl*136 + m]      = (short)f2b(x1v[i][0]);
      st[rl*136 + 16 + m] = (short)f2b(x1v[i][1]);
      st[rl*136 + 32 + m] = (short)f2b(x1v[i][2]);
      st[rl*136 + 48 + m] = (short)f2b(x1v[i][3]);
    }
    // ---- ffn1 A-frags from stage (wave-order LDS) ----
    bf16x8 x10 = *(const bf16x8*)&st[m*136 + quad*8];
    bf16x8 x11 = *(const bf16x8*)&st[m*136 + 32 + quad*8];
    // ---- ffn1: h = relu(x1@W1+b1) into stage ----
    #pragma unroll
    for (int ct=0;ct<8;ct++){
      bf16x8 b0 = *(const bf16x8*)&s_w1[(ct*16+m)*72 + quad*8];
      bf16x8 b1 = *(const bf16x8*)&s_w1[(ct*16+m)*72 + 32 + quad*8];
      f32x4 z = {0.f,0.f,0.f,0.f};
      z = __builtin_amdgcn_mfma_f32_16x16x32_bf16(x10, b0, z, 0,0,0);
      z = __builtin_amdgcn_mfma_f32_16x16x32_bf16(x11, b1, z, 0,0,0);
      #pragma unroll
      for (int i=0;i<4;i++)
        st[(quad*4+i)*136 + ct*16 + m] = (short)f2b(fmaxf(z[i]+b1v[ct], 0.f));
    }
    // ---- ffn2 ----
    bf16x8 h0 = *(const bf16x8*)&st[m*136 + quad*8];
    bf16x8 h1 = *(const bf16x8*)&st[m*136 + 32 + quad*8];
    bf16x8 h2 = *(const bf16x8*)&st[m*136 + 64 + quad*8];
    bf16x8 h3 = *(const bf16x8*)&st[m*136 + 96 + quad*8];
    f32x4 acc2[4];
    #pragma unroll
    for (int ct=0;ct<4;ct++){
      f32x4 z = {0.f,0.f,0.f,0.f};
      z = __builtin_amdgcn_mfma_f32_16x16x32_bf16(h0, *(const bf16x8*)&s_w2[(ct*16+m)*136 + quad*8],      z, 0,0,0);
      z = __builtin_amdgcn_mfma_f32_16x16x32_bf16(h1, *(const bf16x8*)&s_w2[(ct*16+m)*136 + 32 + quad*8], z, 0,0,0);
      z = __builtin_amdgcn_mfma_f32_16x16x32_bf16(h2, *(const bf16x8*)&s_w2[(ct*16+m)*136 + 64 + quad*8], z, 0,0,0);
      z = __builtin_amdgcn_mfma_f32_16x16x32_bf16(h3, *(const bf16x8*)&s_w2[(ct*16+m)*136 + 96 + quad*8], z, 0,0,0);
      acc2[ct] = z;
    }
    // ---- residual (x1 registers) + b2 + LN2 -> stage cols 0..63 ----
    #pragma unroll
    for (int i=0;i<4;i++){
      float v0 = acc2[0][i] + b2v[0] + x1v[i][0];
      float v1 = acc2[1][i] + b2v[1] + x1v[i][1];
      float v2 = acc2[2][i] + b2v[2] + x1v[i][2];
      float v3 = acc2[3][i] + b2v[3] + x1v[i][3];
      float sm = v0+v1+v2+v3;
      float sq = v0*v0+v1*v1+v2*v2+v3*v3;
      #pragma unroll
      for (int mk=1; mk<16; mk<<=1){ sm += __shfl_xor(sm, mk); sq += __shfl_xor(sq, mk); }
      float mean = sm*0.015625f;
      float var  = sq*0.015625f - mean*mean;
      float rs   = rsqrtf(var + 1e-5f);
      int rl = quad*4 + i;
      st[rl*136 + m]      = (short)f2b((v0-mean)*rs*g2[0]+bb2[0]);
      st[rl*136 + 16 + m] = (short)f2b((v1-mean)*rs*g2[1]+bb2[1]);
      st[rl*136 + 32 + m] = (short)f2b((v2-mean)*rs*g2[2]+bb2[2]);
      st[rl*136 + 48 + m] = (short)f2b((v3-mean)*rs*g2[3]+bb2[3]);
    }
    // ---- coalesced store of new x ----
    #pragma unroll
    for (int j=0;j<2;j++){
      int flat = (j*64 + lane)*8;
      int r = flat >> 6, c = flat & 63;
      bf16x8 v = *(const bf16x8*)&st[r*136 + c];
      *(bf16x8*)(xb + (size_t)(rowbase + rt*16 + r)*64 + c) = v;
    }
    // ---- next layer's qkv from x2 (stage-resident); skipped on last layer ----
    if (wqkvT){
      bf16x8 x20 = *(const bf16x8*)&st[m*136 + quad*8];
      bf16x8 x21 = *(const bf16x8*)&st[m*136 + 32 + quad*8];
      #pragma unroll
      for (int half=0; half<2; half++){
        #pragma unroll
        for (int c6=0;c6<6;c6++){
          int ct = half*6 + c6;
          bf16x8 b0 = *(const bf16x8*)&wqkvT[(ct*16+m)*64 + quad*8];
          bf16x8 b1 = *(const bf16x8*)&wqkvT[(ct*16+m)*64 + 32 + quad*8];
          f32x4 z = {0.f,0.f,0.f,0.f};
          z = __builtin_amdgcn_mfma_f32_16x16x32_bf16(x20, b0, z, 0,0,0);
          z = __builtin_amdgcn_mfma_f32_16x16x32_bf16(x21, b1, z, 0,0,0);
          #pragma unroll
          for (int i=0;i<4;i++)
            st[(quad*4+i)*136 + c6*16 + m] = (short)f2b(z[i]);
        }
        #pragma unroll
        for (int j=0;j<3;j++){
          int flat = (j*64 + lane)*8;
          int r = flat / 96, c = flat % 96;
          bf16x8 v = *(const bf16x8*)&st[r*136 + c];
          *(bf16x8*)(qkv + (size_t)(rowbase + rt*16 + r)*192 + half*96 + c) = v;
        }
      }
    }
  }
}

// ---------- heads: FC1 with inline feat assembly (gat_out + obs) ----------
__global__ __launch_bounds__(512) void k_fc1(const unsigned short* __restrict__ xb,
    const float* __restrict__ obs, const int* __restrict__ agents,
    const float* __restrict__ Wr, const float* __restrict__ br,
    const float* __restrict__ Wp1, float* __restrict__ part1){
  constexpr int ROWS=2, COLS=256, CH=384, K=1515, N=512;
  const int chunk = 379;
  __shared__ float s_a[ROWS*CH];
  const int tid = threadIdx.x;
  const int ct = blockIdx.x, rg = blockIdx.y, ks = blockIdx.z;
  const int k0 = ks * chunk;
  const int len = min(K - k0, chunk);
  const int row0 = rg * ROWS;
  #pragma unroll
  for (int rr=0; rr<ROWS; rr++)
    for (int i=tid; i<len; i+=512){
      int k = k0 + i;
      if (k >= AD) s_a[rr*CH + i] = obs[(size_t)(row0+rr)*OBSD + (k-AD)];
    }
  if (ks==0 && tid < ROWS*AD){
    int rr = tid/AD, c = tid%AD;
    int b = row0 + rr;
    const unsigned short* xa = xb + (size_t)agents[b]*HD;
    float a = br[c];
    #pragma unroll 8
    for (int k=0;k<HD;k++) a = fmaf(b2f(xa[k]), Wr[k*AD + c], a);
    s_a[rr*CH + c] = a;
  }
  __syncthreads();
  const int r = tid / COLS, c = tid % COLS;
  const float* wp = Wp1 + (size_t)k0*N + ct*COLS + c;
  const float* ap = s_a + r*CH;
  float acc = 0.f;
  #pragma unroll 8
  for (int k=0;k<len;k++) acc = fmaf(ap[k], wp[(size_t)k*N], acc);
  part1[((size_t)ks*128 + row0 + r)*N + ct*COLS + c] = acc;
}

// ---------- heads: FC2 with reduce+tanh on A-load ----------
__global__ __launch_bounds__(512) void k_fc2(const float* __restrict__ part1,
    const float* __restrict__ bp1, const float* __restrict__ Wp2,
    float* __restrict__ part2){
  constexpr int ROWS=2, COLS=256, CH=256, N=512;
  __shared__ float s_a[ROWS*CH];
  const int tid = threadIdx.x;
  const int ct = blockIdx.x, rg = blockIdx.y, ks = blockIdx.z;
  const int k0 = ks * CH;
  const int row0 = rg * ROWS;
  #pragma unroll
  for (int rr=0; rr<ROWS; rr++)
    for (int i=tid; i<CH; i+=512){
      int k = k0 + i;
      float s = bp1[k];
      #pragma unroll
      for (int j=0;j<4;j++) s += part1[((size_t)j*128 + row0+rr)*512 + k];
      s_a[rr*CH + i] = tanhf(s);
    }
  __syncthreads();
  const int r = tid / COLS, c = tid % COLS;
  const float* wp = Wp2 + (size_t)k0*N + ct*COLS + c;
  const float* ap = s_a + r*CH;
  float acc = 0.f;
  #pragma unroll 8
  for (int k=0;k<CH;k++) acc = fmaf(ap[k], wp[(size_t)k*N], acc);
  part2[((size_t)ks*128 + row0 + r)*N + ct*COLS + c] = acc;
}

// ---------- heads: logits with reduce+tanh on load ----------
__global__ __launch_bounds__(256) void k_logits(const float* __restrict__ part2,
    const float* __restrict__ bp2, const float* __restrict__ Wlog,
    const float* __restrict__ blog, float* __restrict__ out){
  __shared__ float s_f[512];
  __shared__ float s_p[16*AD];
  const int b = blockIdx.x, tid = threadIdx.x;
  for (int i=tid;i<512;i+=256){
    float s = bp2[i] + part2[(size_t)b*512 + i] + part2[(size_t)(128+b)*512 + i];
    s_f[i] = tanhf(s);
  }
  __syncthreads();
  if (tid < 240){
    int c = tid % AD, kc = tid / AD;
    float a = 0.f;
    #pragma unroll 8
    for (int j=0;j<32;j++){ int k = kc*32 + j; a = fmaf(s_f[k], Wlog[k*AD + c], a); }
    s_p[tid] = a;
  }
  __syncthreads();
  if (tid < AD){
    float a = blog[tid];
    #pragma unroll
    for (int kc=0;kc<16;kc++) a += s_p[kc*AD + tid];
    out[(size_t)b*AD + tid] = a;
  }
}

// ---------- heads: value split-K GEMM ----------
template<int ROWS, int COLS, int CH, int KS, int N>
__global__ __launch_bounds__(ROWS*COLS) void k_gemm_part(
    const float* __restrict__ A, int lda, int K,
    const float* __restrict__ W, float* __restrict__ part){
  constexpr int BT = ROWS*COLS;
  __shared__ float s_a[ROWS*CH];
  const int tid = threadIdx.x;
  const int ct = blockIdx.x, rg = blockIdx.y, ks = blockIdx.z;
  const int chunk = (K + KS - 1) / KS;
  const int k0 = ks * chunk;
  const int len = min(K - k0, chunk);
  const int row0 = rg * ROWS;
  #pragma unroll
  for (int rr=0; rr<ROWS; rr++)
    for (int i=tid; i<len; i+=BT)
      s_a[rr*CH + i] = A[(size_t)(row0+rr)*lda + k0 + i];
  __syncthreads();
  const int r = tid / COLS, c = tid % COLS;
  const float* wp = W + (size_t)k0*N + ct*COLS + c;
  const float* ap = s_a + r*CH;
  float acc = 0.f;
  #pragma unroll 8
  for (int k=0;k<len;k++) acc = fmaf(ap[k], wp[(size_t)k*N], acc);
  part[((size_t)ks*128 + row0 + r)*N + ct*COLS + c] = acc;
}

// ---------- heads: value finish with reduce+tanh on load ----------
__global__ __launch_bounds__(128) void k_vfin(const float* __restrict__ partv,
    const float* __restrict__ bv1, const float* __restrict__ Wv2,
    const float* __restrict__ bv2, const float* __restrict__ Wvo,
    const float* __restrict__ bvo, float* __restrict__ out){
  __shared__ float s_v[128];
  __shared__ float s_r[128];
  const int b = blockIdx.x, tid = threadIdx.x;
  {
    float s = bv1[tid];
    #pragma unroll
    for (int j=0;j<8;j++) s += partv[((size_t)j*128 + b)*128 + tid];
    s_v[tid] = tanhf(s);
  }
  __syncthreads();
  float a = bv2[tid];
  #pragma unroll 8
  for (int k=0;k<128;k++) a = fmaf(s_v[k], Wv2[k*128 + tid], a);
  s_r[tid] = tanhf(a) * Wvo[tid];
  __syncthreads();
  if (tid < 64){
    float v = s_r[tid] + s_r[tid+64];
    #pragma unroll
    for (int m=32;m>=1;m>>=1) v += __shfl_xor(v, m);
    if (tid==0) out[GRAPHS*AD + b] = v + bvo[0];
  }
}

// ---------- launch ----------
extern "C" void kernel_launch(void* const* d_in, const int* in_sizes, int n_in,
                              void* d_out, int out_size, void* d_ws, size_t ws_size,
                              hipStream_t stream) {
  (void)in_sizes; (void)n_in; (void)out_size; (void)ws_size;
  const float* nf     = (const float*)d_in[0];
  const float* obs    = (const float*)d_in[1];
  const int*   esrc   = (const int*)d_in[2];
  const int*   edst   = (const int*)d_in[3];
  const int*   agents = (const int*)d_in[4];
  const float* Win    = (const float*)d_in[5];
  const float* Wq     = (const float*)d_in[6];
  const float* Wk     = (const float*)d_in[7];
  const float* Wv     = (const float*)d_in[8];
  const float* Wo     = (const float*)d_in[9];
  const float* ln1g   = (const float*)d_in[10];
  const float* ln1b   = (const float*)d_in[11];
  const float* W1     = (const float*)d_in[12];
  const float* b1     = (const float*)d_in[13];
  const float* W2     = (const float*)d_in[14];
  const float* b2     = (const float*)d_in[15];
  const float* ln2g   = (const float*)d_in[16];
  const float* ln2b   = (const float*)d_in[17];
  const float* Wr     = (const float*)d_in[18];
  const float* br     = (const float*)d_in[19];
  const float* Wp1    = (const float*)d_in[20];
  const float* bp1    = (const float*)d_in[21];
  const float* Wp2    = (const float*)d_in[22];
  const float* bp2    = (const float*)d_in[23];
  const float* Wlog   = (const float*)d_in[24];
  const float* blog   = (const float*)d_in[25];
  const float* Wv1    = (const float*)d_in[26];
  const float* bv1    = (const float*)d_in[27];
  const float* Wv2    = (const float*)d_in[28];
  const float* bv2    = (const float*)d_in[29];
  const float* Wvo    = (const float*)d_in[30];
  const float* bvo    = (const float*)d_in[31];
  float* out = (float*)d_out;

  // workspace layout (all bf16 activations)
  unsigned short* xb      = (unsigned short*)d_ws;             // TOTN*64 bf16
  unsigned short* qkv     = xb + (size_t)TOTN*HD;              // TOTN*192 bf16
  unsigned short* attn_in = qkv + (size_t)TOTN*192;            // TOTN*64 bf16
  unsigned short* wpack   = attn_in + (size_t)TOTN*HD;         // 131072 bf16
  int* cnt     = (int*)(wpack + 131072);                       // TOTN
  int* rstart  = cnt + TOTN;
  int* cursor  = rstart + TOTN;
  int* esorted = cursor + TOTN;                                // TOTE
  // head partials (float) after the int region
  float* part1 = (float*)(esorted + TOTE);                     // 4*128*512
  float* part2 = part1 + 4*128*512;                            // 2*128*512
  float* partv = part2 + 2*128*512;                            // 8*128*128

  // weight prep + CSR build (edge topology is layer-invariant)
  k_wprep  <<<512, 256, 0, stream>>>(Wq, Wk, Wv, Wo, W1, W2, wpack);
  k_zero   <<<TOTN/256, 256, 0, stream>>>(cnt);
  k_hist   <<<TOTE/256, 256, 0, stream>>>(edst, cnt);
  k_scan   <<<GRAPHS, 1024, 0, stream>>>(cnt, rstart, cursor);
  k_scatter<<<TOTE/256, 256, 0, stream>>>(esrc, edst, cursor, esorted);

  k_in<<<TOTN/256, 256, 0, stream>>>(nf, Win, xb);
  k_qkv_m<<<TOTN/256, 256, 0, stream>>>(xb, wpack, qkv);   // layer 0 qkv
  for (int l=0; l<4; l++){
    const unsigned short* wl = wpack + l*32768;
    const unsigned short* wqkv_next = (l<3) ? (wpack + (l+1)*32768) : nullptr;
    k_edge2   <<<TOTN/16, 256, 0, stream>>>(qkv, rstart, cnt, esorted, attn_in);
    k_attn_ffn<<<TOTN/256, 256, 0, stream>>>(attn_in, xb,
                                             wl + 12288,             // woT
                                             wl + 16384, b1 + l*128, // w1T, b1
                                             wl + 24576, b2 + l*64,  // w2T, b2
                                             ln1g + l*64, ln1b + l*64,
                                             ln2g + l*64, ln2b + l*64,
                                             wqkv_next, qkv);
  }
  // policy head (3 dispatches)
  k_fc1   <<<dim3(2,64,4), 512, 0, stream>>>(xb, obs, agents, Wr, br, Wp1, part1);
  k_fc2   <<<dim3(2,64,2), 512, 0, stream>>>(part1, bp1, Wp2, part2);
  k_logits<<<GRAPHS, 256, 0, stream>>>(part2, bp2, Wlog, blog, out);
  // value head (2 dispatches)
  k_gemm_part<4,128,192,8,128><<<dim3(1,32,8), 512, 0, stream>>>(obs, 1500, 1500, Wv1, partv);
  k_vfin  <<<GRAPHS, 128, 0, stream>>>(partv, bv1, Wv2, bv2, Wvo, bvo, out);
}